// Round 13
// baseline (674.059 us; speedup 1.0000x reference)
//
#include <hip/hip_runtime.h>
#include <math.h>

#define THR 256

typedef __attribute__((ext_vector_type(8))) short bf16x8;
typedef __attribute__((ext_vector_type(4))) float f32x4;

// ---------------- CSR build ----------------

// Detect whether edge_index buffer is int64 (high words all zero) or int32.
__global__ void k_detect(const int* __restrict__ w, int* __restrict__ flag) {
  int i = blockIdx.x * blockDim.x + threadIdx.x;
  if (i < 4096) {
    if (w[2 * i + 1] != 0) atomicOr(flag, 1);
  }
}

__device__ __forceinline__ int load_idx(const int* __restrict__ w, int pos, int is32) {
  return is32 ? w[pos] : w[2 * pos];
}

__global__ void k_count(const int* __restrict__ ei, const int* __restrict__ flag,
                        int* __restrict__ cnt, int E) {
  int e = blockIdx.x * blockDim.x + threadIdx.x;
  if (e < E) {
    int is32 = *flag;
    int d = load_idx(ei, E + e, is32);
    atomicAdd(&cnt[d], 1);
  }
}

__global__ __launch_bounds__(1024) void k_scan(int* __restrict__ cnt_cur, int* __restrict__ off, int n) {
  __shared__ int part[1024];
  int tid = threadIdx.x;
  int chunk = (n + 1023) / 1024;
  int s0 = tid * chunk;
  int s1 = min(s0 + chunk, n);
  int s = 0;
  for (int i = s0; i < s1; ++i) s += cnt_cur[i];
  part[tid] = s;
  __syncthreads();
  for (int d = 1; d < 1024; d <<= 1) {
    int v = (tid >= d) ? part[tid - d] : 0;
    __syncthreads();
    part[tid] += v;
    __syncthreads();
  }
  int excl = (tid == 0) ? 0 : part[tid - 1];
  for (int i = s0; i < s1; ++i) {
    int c = cnt_cur[i];
    off[i] = excl;
    cnt_cur[i] = excl;   // cursor copy for scatter
    excl += c;
  }
  if (tid == 1023) off[n] = part[1023];
}

__global__ void k_scatter(const int* __restrict__ ei, const int* __restrict__ flag,
                          int* __restrict__ cur, int* __restrict__ pos,
                          int* __restrict__ ssrc, int E) {
  int e = blockIdx.x * blockDim.x + threadIdx.x;
  if (e < E) {
    int is32 = *flag;
    int d = load_idx(ei, E + e, is32);
    int s = load_idx(ei, e, is32);
    int p = atomicAdd(&cur[d], 1);
    pos[e] = p;
    ssrc[p] = s;
  }
}

// ---------------- weight prep (layer 2 only) ----------------

__global__ void k_fold_att(const float* __restrict__ W, const float* __restrict__ att,
                           float* __restrict__ waj, float* __restrict__ wai,
                           int Cin, int H) {
  int i = blockIdx.x * blockDim.x + threadIdx.x;
  if (i >= Cin * H) return;
  int k = i / H, h = i % H;
  float sj = 0.f, si = 0.f;
  for (int d = 0; d < 64; ++d) {
    float w = W[k * (H * 64) + h * 64 + d];
    sj = fmaf(w, att[h * 192 + d], sj);
    si = fmaf(w, att[h * 192 + 64 + d], si);
  }
  waj[k * H + h] = sj;
  wai[k * H + h] = si;
}

template <int CIN, int H>
__global__ void k_node_dots(const float* __restrict__ xin, const float* __restrict__ waj,
                            const float* __restrict__ wai, float* __restrict__ ajd,
                            float* __restrict__ aid, int N) {
  int n = blockIdx.x * blockDim.x + threadIdx.x;
  if (n >= N) return;
  float sj[H], si[H];
#pragma unroll
  for (int h = 0; h < H; ++h) { sj[h] = 0.f; si[h] = 0.f; }
  const float* xr = xin + (size_t)n * CIN;
#pragma unroll 4
  for (int k = 0; k < CIN; ++k) {
    float xv = xr[k];
#pragma unroll
    for (int h = 0; h < H; ++h) {
      sj[h] = fmaf(xv, waj[k * H + h], sj[h]);
      si[h] = fmaf(xv, wai[k * H + h], si[h]);
    }
  }
#pragma unroll
  for (int h = 0; h < H; ++h) {
    ajd[(size_t)n * H + h] = sj[h];
    aid[(size_t)n * H + h] = si[h];
  }
}

// ---------------- per-node projection GEMM with fused att-dots (layers 0,1) ----------------
// xh[n,j] = sum_k xin[n,k] * W[k,j]   (64 output cols, lane j owns col j)
// ajd[n]  = sum_j xh[n,j] * att[j] ;  aid[n] = sum_j xh[n,j] * att[64+j]
template <int F>
__global__ __launch_bounds__(256) void k_gemm_nh(
    const float* __restrict__ xin, const float* __restrict__ W,
    const float* __restrict__ att, float* __restrict__ xh,
    float* __restrict__ ajd, float* __restrict__ aid, int N) {
  const int wave = threadIdx.x >> 6, lane = threadIdx.x & 63;
  float w[F];
#pragma unroll
  for (int k = 0; k < F; ++k) w[k] = W[k * 64 + lane];
  const float aj = att[lane], ai = att[64 + lane];
  for (int n = blockIdx.x * 4 + wave; n < N; n += gridDim.x * 4) {
    const float* xr = xin + (size_t)n * F;
    float a = 0.f;
#pragma unroll
    for (int k = 0; k < F; ++k) a = fmaf(xr[k], w[k], a);
    xh[(size_t)n * 64 + lane] = a;
    float sj = a * aj, si = a * ai;
#pragma unroll
    for (int o = 32; o > 0; o >>= 1) {
      sj += __shfl_xor(sj, o, 64);
      si += __shfl_xor(si, o, 64);
    }
    if (lane == 0) { ajd[n] = sj; aid[n] = si; }
  }
}

// ---------------- MFMA-based edge scalar ep ----------------

__device__ __forceinline__ unsigned short bf16_rne(float x) {
  unsigned int u = __float_as_uint(x);
  return (unsigned short)((u + 0x7FFFu + ((u >> 16) & 1u)) >> 16);
}

// Build weight fragments (A-operand of the swapped MFMA).
// Concat weight matrix We_cat: 16 x 384 (cols 0-63 We0, 64-127 We1, 128-383 We2).
// Split f32 = hi + lo (bf16 each). K=32 arrangement matches the edge fragments:
// k<16 pairs with edge-hi, k>=16 pairs with edge-lo. B1 = [Whi;Whi], B2 = [Wlo;0].
// Fragment layout (operand-symmetric): lane l holds row/col = T*16 + (l&15),
// k = (l>>4)*8 + j, j=0..7.  avec[384]: a_p coefficient per concat column.
__global__ void k_prep_b(const float* __restrict__ We0, const float* __restrict__ We1,
                         const float* __restrict__ We2,
                         const float* __restrict__ att0, const float* __restrict__ att1,
                         const float* __restrict__ att2,
                         bf16x8* __restrict__ B1, bf16x8* __restrict__ B2,
                         float* __restrict__ avec) {
  int i = blockIdx.x * blockDim.x + threadIdx.x;
  if (i < 24 * 64) {
    int T = i >> 6, l = i & 63;
    int col = T * 16 + (l & 15);
    int grp = l >> 4;
    bf16x8 b1, b2;
#pragma unroll
    for (int j = 0; j < 8; ++j) {
      int kk = grp * 8 + j;     // 0..31
      int ks = kk & 15;         // source k (both halves use same Whi)
      float w;
      if (col < 64)        w = We0[ks * 64 + col];
      else if (col < 128)  w = We1[ks * 64 + (col - 64)];
      else                 w = We2[ks * 256 + (col - 128)];
      unsigned short hi = bf16_rne(w);
      float hif = __uint_as_float((unsigned int)hi << 16);
      unsigned short lo = bf16_rne(w - hif);
      b1[j] = (short)hi;
      b2[j] = (kk < 16) ? (short)lo : (short)0;
    }
    B1[i] = b1;
    B2[i] = b2;
  } else if (i < 24 * 64 + 384) {
    int col = i - 24 * 64;
    float a;
    if (col < 64)        a = att0[128 + col];
    else if (col < 128)  a = att1[128 + (col - 64)];
    else {
      int c = col - 128;
      a = att2[(c >> 6) * 192 + 128 + (c & 63)];
    }
    avec[col] = a;
  }
}

// One wave = 64 edges (4 edge fragments of 16, used as the MFMA *B* operand).
// A operand = weight tiles (d-outputs on the M side). D tile: col(lane&15)=edge,
// row(grp*4+reg)=d. The relu*a_p reduction over d is therefore in-register
// (4 FMAs/tile) + one 2-stage cross-group shfl per (seg,frag) — no 16-lane
// reduce, no serialized scatter. ep2 accumulates in a float4 across segs 2-5
// and stores once (no 4x write amplification).
__global__ __launch_bounds__(256) void k_ep_mfma(
    const float* __restrict__ ea, const bf16x8* __restrict__ B1,
    const bf16x8* __restrict__ B2, const float* __restrict__ avec,
    const int* __restrict__ pos, float* __restrict__ ep0,
    float* __restrict__ ep1, float* __restrict__ ep2, int E) {
  const int lane = threadIdx.x & 63;
  const int wv = threadIdx.x >> 6;
  const long e0 = ((long)blockIdx.x * 4 + wv) * 64;
  const int grp = lane >> 4;        // 0..3
  const int row = lane & 15;        // edge index within fragment (B: N-col)
  const int kc = (grp & 1) * 8;     // which 8 source-k's this lane group loads
  const bool lo_grp = grp >= 2;     // groups 2,3 carry the lo halves (k 16..31)

  // ---- edge fragments (B operand) ----
  bf16x8 Bf[4];
#pragma unroll
  for (int f = 0; f < 4; ++f) {
    long e = e0 + f * 16 + row;
    if (e >= E) e = E - 1;          // clamp; stores guarded later
    const float* ar = ea + e * 16 + kc;
    float4 u0 = *reinterpret_cast<const float4*>(ar);
    float4 u1 = *reinterpret_cast<const float4*>(ar + 4);
    float v0 = u0.x, v1 = u0.y, v2 = u0.z, v3 = u0.w;
    float v4 = u1.x, v5 = u1.y, v6 = u1.z, v7 = u1.w;
    bf16x8 a;
#define CVT(J, V)                                                        \
    {                                                                    \
      unsigned short hi = bf16_rne(V);                                   \
      float hif = __uint_as_float((unsigned int)hi << 16);               \
      unsigned short lo = bf16_rne((V) - hif);                           \
      a[J] = (short)(lo_grp ? lo : hi);                                  \
    }
    CVT(0, v0) CVT(1, v1) CVT(2, v2) CVT(3, v3)
    CVT(4, v4) CVT(5, v5) CVT(6, v6) CVT(7, v7)
#undef CVT
    Bf[f] = a;
  }

  // ---- CSR positions (hoisted; used by lanes 0..15) ----
  int pf[4];
#pragma unroll
  for (int f = 0; f < 4; ++f) {
    long e = e0 + f * 16 + row;
    pf[f] = pos[e < E ? e : (E - 1)];
  }

  float4 v2acc[4];

  // ---- 6 segments x 4 tiles, d on the M (row) side ----
#pragma unroll
  for (int seg = 0; seg < 6; ++seg) {
    float sp0 = 0.f, sp1 = 0.f, sp2 = 0.f, sp3 = 0.f;
#pragma unroll
    for (int tt = 0; tt < 4; ++tt) {
      const int T = seg * 4 + tt;
      bf16x8 a1 = B1[T * 64 + lane];
      bf16x8 a2 = B2[T * 64 + lane];
      // a_p values for this lane's 4 d-rows: d = T*16 + grp*4 + r
      float4 av = *reinterpret_cast<const float4*>(avec + T * 16 + (grp << 2));
#define EPTILE(SP, F)                                                     \
      {                                                                   \
        f32x4 acc = {0.f, 0.f, 0.f, 0.f};                                 \
        acc = __builtin_amdgcn_mfma_f32_16x16x32_bf16(a1, Bf[F], acc, 0, 0, 0); \
        acc = __builtin_amdgcn_mfma_f32_16x16x32_bf16(a2, Bf[F], acc, 0, 0, 0); \
        SP = fmaf(fmaxf(acc[0], 0.f), av.x, SP);                          \
        SP = fmaf(fmaxf(acc[1], 0.f), av.y, SP);                          \
        SP = fmaf(fmaxf(acc[2], 0.f), av.z, SP);                          \
        SP = fmaf(fmaxf(acc[3], 0.f), av.w, SP);                          \
      }
      EPTILE(sp0, 0) EPTILE(sp1, 1) EPTILE(sp2, 2) EPTILE(sp3, 3)
#undef EPTILE
    }
    // combine the 4 lane-groups (each holds a quarter of the 64 d's)
    sp0 += __shfl_xor(sp0, 16, 64); sp0 += __shfl_xor(sp0, 32, 64);
    sp1 += __shfl_xor(sp1, 16, 64); sp1 += __shfl_xor(sp1, 32, 64);
    sp2 += __shfl_xor(sp2, 16, 64); sp2 += __shfl_xor(sp2, 32, 64);
    sp3 += __shfl_xor(sp3, 16, 64); sp3 += __shfl_xor(sp3, 32, 64);

    float spf[4] = {sp0, sp1, sp2, sp3};
    if (seg == 0) {
      if (lane < 16) {
#pragma unroll
        for (int f = 0; f < 4; ++f)
          if (e0 + f * 16 + lane < E) ep0[pf[f]] = spf[f];
      }
    } else if (seg == 1) {
      if (lane < 16) {
#pragma unroll
        for (int f = 0; f < 4; ++f)
          if (e0 + f * 16 + lane < E) ep1[pf[f]] = spf[f];
      }
    } else {
#pragma unroll
      for (int f = 0; f < 4; ++f) {
        if (seg == 2) v2acc[f].x = spf[f];
        if (seg == 3) v2acc[f].y = spf[f];
        if (seg == 4) v2acc[f].z = spf[f];
        if (seg == 5) v2acc[f].w = spf[f];
      }
    }
  }
  if (lane < 16) {
#pragma unroll
    for (int f = 0; f < 4; ++f)
      if (e0 + f * 16 + lane < E)
        reinterpret_cast<float4*>(ep2)[pf[f]] = v2acc[f];
  }
}

// ---------------- fused attention softmax + aggregate ----------------

template <int H>
__device__ __forceinline__ void loadH(const float* __restrict__ p, float* v) {
  if constexpr (H == 4) {
    float4 t = *reinterpret_cast<const float4*>(p);
    v[0] = t.x; v[1] = t.y; v[2] = t.z; v[3] = t.w;
  } else {
    v[0] = *p;
  }
}

// one wave per node, all H heads together.
// agg[n, h*F + f] = sum_e alpha_{e,h} * hin[src_e, f]   (+ optional ELU)
template <int F, int H, bool ELU_OUT>
__global__ __launch_bounds__(256) void k_attn_agg(
    const int* __restrict__ off, const int* __restrict__ ssrc,
    const float* __restrict__ hin, const float* __restrict__ ajd,
    const float* __restrict__ aid, const float* __restrict__ ep,
    float* __restrict__ outbuf, int N) {
  constexpr int FPL = F / 64;
  __shared__ float ls_alpha[4][64 * H];
  __shared__ int ls_src[4][64];
  const int wave = threadIdx.x >> 6, lane = threadIdx.x & 63;
  float* const la = ls_alpha[wave];
  int* const lsrc = ls_src[wave];

  for (int n = blockIdx.x * 4 + wave; n < N; n += gridDim.x * 4) {
    const int o0 = off[n];
    const int deg = off[n + 1] - o0;
    float aidn[H];
    loadH<H>(aid + (size_t)n * H, aidn);

    // ---- pass 1: online softmax stats (lane-parallel over edges) ----
    float m[H], s[H];
#pragma unroll
    for (int h = 0; h < H; ++h) { m[h] = -1e30f; s[h] = 0.f; }
    for (int i = lane; i < deg; i += 64) {
      int sr = ssrc[o0 + i];
      float aj[H], pv[H];
      loadH<H>(ajd + (size_t)sr * H, aj);
      loadH<H>(ep + (size_t)(o0 + i) * H, pv);
#pragma unroll
      for (int h = 0; h < H; ++h) {
        float sc = aj[h] + aidn[h] + pv[h];
        sc = sc > 0.f ? sc : 0.2f * sc;
        float mn = fmaxf(m[h], sc);
        s[h] = s[h] * __expf(m[h] - mn) + __expf(sc - mn);
        m[h] = mn;
      }
    }
#pragma unroll
    for (int o = 32; o > 0; o >>= 1) {
#pragma unroll
      for (int h = 0; h < H; ++h) {
        float m2 = __shfl_xor(m[h], o, 64);
        float s2 = __shfl_xor(s[h], o, 64);
        float mn = fmaxf(m[h], m2);
        s[h] = s[h] * __expf(m[h] - mn) + s2 * __expf(m2 - mn);
        m[h] = mn;
      }
    }
    float inv[H];
#pragma unroll
    for (int h = 0; h < H; ++h) inv[h] = 1.f / (s[h] + 1e-16f);

    // ---- pass 2: chunked alpha -> LDS, then 4-way unrolled gather+FMA ----
    float acc[H][FPL];
#pragma unroll
    for (int h = 0; h < H; ++h)
#pragma unroll
      for (int c = 0; c < FPL; ++c) acc[h][c] = 0.f;

    for (int base = 0; base < deg; base += 64) {
      const int cnt = min(64, deg - base);
      if (lane < cnt) {
        int i = base + lane;
        int sr = ssrc[o0 + i];
        lsrc[lane] = sr;
        float aj[H], pv[H];
        loadH<H>(ajd + (size_t)sr * H, aj);
        loadH<H>(ep + (size_t)(o0 + i) * H, pv);
#pragma unroll
        for (int h = 0; h < H; ++h) {
          float sc = aj[h] + aidn[h] + pv[h];
          sc = sc > 0.f ? sc : 0.2f * sc;
          la[lane * H + h] = __expf(sc - m[h]) * inv[h];
        }
      }
      asm volatile("s_waitcnt lgkmcnt(0)" ::: "memory");

      int j = 0;
      for (; j + 4 <= cnt; j += 4) {
        int srj[4];
        float av[4][H];
#pragma unroll
        for (int u = 0; u < 4; ++u) {
          srj[u] = lsrc[j + u];
          loadH<H>(la + (j + u) * H, av[u]);
        }
        float v[4][FPL];
#pragma unroll
        for (int u = 0; u < 4; ++u) {
          const float* hr = hin + (size_t)srj[u] * F + lane;
#pragma unroll
          for (int c = 0; c < FPL; ++c) v[u][c] = hr[c * 64];
        }
#pragma unroll
        for (int u = 0; u < 4; ++u)
#pragma unroll
          for (int h = 0; h < H; ++h)
#pragma unroll
            for (int c = 0; c < FPL; ++c)
              acc[h][c] = fmaf(av[u][h], v[u][c], acc[h][c]);
      }
      for (; j < cnt; ++j) {
        int sr = lsrc[j];
        float av[H];
        loadH<H>(la + j * H, av);
        const float* hr = hin + (size_t)sr * F + lane;
#pragma unroll
        for (int h = 0; h < H; ++h)
#pragma unroll
          for (int c = 0; c < FPL; ++c)
            acc[h][c] = fmaf(av[h], hr[c * 64], acc[h][c]);
      }
    }

    float* ob = outbuf + (size_t)n * (H * F);
#pragma unroll
    for (int h = 0; h < H; ++h)
#pragma unroll
      for (int c = 0; c < FPL; ++c) {
        float v = acc[h][c];
        if (ELU_OUT) v = (v > 0.f) ? v : expm1f(v);
        ob[h * F + c * 64 + lane] = v;
      }
  }
}

// ---------------- post GEMM (layer 2): out[n, j] = agg[n, (j>>6)*64 + :] . W2[:, j] ----------------
// Thread owns column j = threadIdx.x (256 cols); whole block works one node per
// iteration. agg row slice loaded as float4 (L1 broadcast within head-group);
// 4 independent accumulator chains break the FMA dependency; 2048 blocks for TLP.

template <bool ELU_ACT>
__global__ __launch_bounds__(256) void k_post_col(const float* __restrict__ agg,
                                                  const float* __restrict__ W,
                                                  float* __restrict__ out, int N) {
  const int j = threadIdx.x;          // output column 0..255
  const int h = j >> 6;
  float w[64];
#pragma unroll
  for (int k = 0; k < 64; ++k) w[k] = W[k * 256 + j];
  for (int n = blockIdx.x; n < N; n += gridDim.x) {
    const float4* ag4 = reinterpret_cast<const float4*>(agg + (size_t)n * 256 + h * 64);
    float a0 = 0.f, a1 = 0.f, a2 = 0.f, a3 = 0.f;
#pragma unroll
    for (int q = 0; q < 16; ++q) {
      float4 v = ag4[q];
      a0 = fmaf(v.x, w[4 * q + 0], a0);
      a1 = fmaf(v.y, w[4 * q + 1], a1);
      a2 = fmaf(v.z, w[4 * q + 2], a2);
      a3 = fmaf(v.w, w[4 * q + 3], a3);
    }
    float a = (a0 + a1) + (a2 + a3);
    if (ELU_ACT) a = (a > 0.f) ? a : expm1f(a);
    out[(size_t)n * 256 + j] = a;
  }
}

// ---------------- launch ----------------

extern "C" void kernel_launch(void* const* d_in, const int* in_sizes, int n_in,
                              void* d_out, int out_size, void* d_ws, size_t ws_size,
                              hipStream_t stream) {
  const float* x    = (const float*)d_in[0];
  const int*   ei   = (const int*)d_in[1];
  const float* ea   = (const float*)d_in[2];
  const float* W0   = (const float*)d_in[3];
  const float* We0  = (const float*)d_in[4];
  const float* att0 = (const float*)d_in[5];
  const float* W1   = (const float*)d_in[6];
  const float* We1  = (const float*)d_in[7];
  const float* att1 = (const float*)d_in[8];
  const float* W2   = (const float*)d_in[9];
  const float* We2  = (const float*)d_in[10];
  const float* att2 = (const float*)d_in[11];
  float* out = (float*)d_out;

  const int N = in_sizes[0] / 128;   // 50000
  const int E = in_sizes[2] / 16;    // 800000

  char* p = (char*)d_ws;
  auto alloc = [&](size_t bytes) {
    char* r = p;
    p += (bytes + 255) & ~(size_t)255;
    return r;
  };
  int*   flag = (int*)  alloc(sizeof(int));
  int*   off  = (int*)  alloc((size_t)(N + 1) * sizeof(int));
  int*   cur  = (int*)  alloc((size_t)N * sizeof(int));
  int*   pos  = (int*)  alloc((size_t)E * sizeof(int));
  int*   ssrc = (int*)  alloc((size_t)E * sizeof(int));
  bf16x8* B1  = (bf16x8*)alloc(24 * 64 * sizeof(bf16x8));
  bf16x8* B2  = (bf16x8*)alloc(24 * 64 * sizeof(bf16x8));
  float* avec = (float*)alloc(384 * sizeof(float));
  float* waj2 = (float*)alloc(256 * sizeof(float));
  float* wai2 = (float*)alloc(256 * sizeof(float));
  float* ajdA = (float*)alloc((size_t)N * sizeof(float));
  float* aidA = (float*)alloc((size_t)N * sizeof(float));
  float* ajd2 = (float*)alloc((size_t)N * 4 * sizeof(float));
  float* aid2 = (float*)alloc((size_t)N * 4 * sizeof(float));
  float* ep0  = (float*)alloc((size_t)E * sizeof(float));
  float* ep1  = (float*)alloc((size_t)E * sizeof(float));
  float* ep2  = (float*)alloc((size_t)E * 4 * sizeof(float));
  float* xh0  = (float*)alloc((size_t)N * 64 * sizeof(float));
  float* h1   = (float*)alloc((size_t)N * 64 * sizeof(float));
  float* xh1  = (float*)alloc((size_t)N * 64 * sizeof(float));
  float* h2   = (float*)alloc((size_t)N * 64 * sizeof(float));
  float* aggL2= (float*)alloc((size_t)N * 256 * sizeof(float));

  const int eb = (E + THR - 1) / THR;
  const int nb = (N + THR - 1) / THR;
  const int ab = (N + 3) / 4;
  const int gb = min(ab, 2048);

  hipMemsetAsync(flag, 0, sizeof(int), stream);
  hipMemsetAsync(cur, 0, (size_t)N * sizeof(int), stream);

  k_detect<<<16, THR, 0, stream>>>(ei, flag);
  k_count<<<eb, THR, 0, stream>>>(ei, flag, cur, E);
  k_scan<<<1, 1024, 0, stream>>>(cur, off, N);
  k_scatter<<<eb, THR, 0, stream>>>(ei, flag, cur, pos, ssrc, E);

  k_prep_b<<<8, THR, 0, stream>>>(We0, We1, We2, att0, att1, att2, B1, B2, avec);
  // 256 edges per block (4 waves x 64 edges)
  k_ep_mfma<<<(E + 255) / 256, THR, 0, stream>>>(ea, B1, B2, avec, pos,
                                                 ep0, ep1, ep2, E);

  // layer 0: xh0 = x@W0 (+ fused a_j/a_i dots), aggregate in output space, ELU fused
  k_gemm_nh<128><<<gb, THR, 0, stream>>>(x, W0, att0, xh0, ajdA, aidA, N);
  k_attn_agg<64, 1, true><<<ab, THR, 0, stream>>>(off, ssrc, xh0, ajdA, aidA, ep0, h1, N);

  // layer 1: xh1 = h1@W1, aggregate, ELU fused
  k_gemm_nh<64><<<gb, THR, 0, stream>>>(h1, W1, att1, xh1, ajdA, aidA, N);
  k_attn_agg<64, 1, true><<<ab, THR, 0, stream>>>(off, ssrc, xh1, ajdA, aidA, ep1, h2, N);

  // layer 2: input-space aggregation (64 < 4*64), then post GEMM
  k_fold_att<<<1, 256, 0, stream>>>(W2, att2, waj2, wai2, 64, 4);
  k_node_dots<64, 4><<<nb, THR, 0, stream>>>(h2, waj2, wai2, ajd2, aid2, N);
  k_attn_agg<64, 4, false><<<ab, THR, 0, stream>>>(off, ssrc, h2, ajd2, aid2, ep2, aggL2, N);
  k_post_col<false><<<2048, THR, 0, stream>>>(aggL2, W2, out, N);
}

// Round 14
// 574.675 us; speedup vs baseline: 1.1729x; 1.1729x over previous
//
#include <hip/hip_runtime.h>
#include <math.h>

#define THR 256

typedef __attribute__((ext_vector_type(8))) short bf16x8;
typedef __attribute__((ext_vector_type(4))) float f32x4;

// ---------------- CSR build ----------------

// Detect whether edge_index buffer is int64 (high words all zero) or int32.
__global__ void k_detect(const int* __restrict__ w, int* __restrict__ flag) {
  int i = blockIdx.x * blockDim.x + threadIdx.x;
  if (i < 4096) {
    if (w[2 * i + 1] != 0) atomicOr(flag, 1);
  }
}

__device__ __forceinline__ int load_idx(const int* __restrict__ w, int pos, int is32) {
  return is32 ? w[pos] : w[2 * pos];
}

__global__ void k_count(const int* __restrict__ ei, const int* __restrict__ flag,
                        int* __restrict__ cnt, int E) {
  int e = blockIdx.x * blockDim.x + threadIdx.x;
  if (e < E) {
    int is32 = *flag;
    int d = load_idx(ei, E + e, is32);
    atomicAdd(&cnt[d], 1);
  }
}

__global__ __launch_bounds__(1024) void k_scan(int* __restrict__ cnt_cur, int* __restrict__ off, int n) {
  __shared__ int part[1024];
  int tid = threadIdx.x;
  int chunk = (n + 1023) / 1024;
  int s0 = tid * chunk;
  int s1 = min(s0 + chunk, n);
  int s = 0;
  for (int i = s0; i < s1; ++i) s += cnt_cur[i];
  part[tid] = s;
  __syncthreads();
  for (int d = 1; d < 1024; d <<= 1) {
    int v = (tid >= d) ? part[tid - d] : 0;
    __syncthreads();
    part[tid] += v;
    __syncthreads();
  }
  int excl = (tid == 0) ? 0 : part[tid - 1];
  for (int i = s0; i < s1; ++i) {
    int c = cnt_cur[i];
    off[i] = excl;
    cnt_cur[i] = excl;   // cursor copy for scatter
    excl += c;
  }
  if (tid == 1023) off[n] = part[1023];
}

__global__ void k_scatter(const int* __restrict__ ei, const int* __restrict__ flag,
                          int* __restrict__ cur, int* __restrict__ pos,
                          int* __restrict__ ssrc, int E) {
  int e = blockIdx.x * blockDim.x + threadIdx.x;
  if (e < E) {
    int is32 = *flag;
    int d = load_idx(ei, E + e, is32);
    int s = load_idx(ei, e, is32);
    int p = atomicAdd(&cur[d], 1);
    pos[e] = p;
    ssrc[p] = s;
  }
}

// ---------------- weight prep (layer 2 only) ----------------

__global__ void k_fold_att(const float* __restrict__ W, const float* __restrict__ att,
                           float* __restrict__ waj, float* __restrict__ wai,
                           int Cin, int H) {
  int i = blockIdx.x * blockDim.x + threadIdx.x;
  if (i >= Cin * H) return;
  int k = i / H, h = i % H;
  float sj = 0.f, si = 0.f;
  for (int d = 0; d < 64; ++d) {
    float w = W[k * (H * 64) + h * 64 + d];
    sj = fmaf(w, att[h * 192 + d], sj);
    si = fmaf(w, att[h * 192 + 64 + d], si);
  }
  waj[k * H + h] = sj;
  wai[k * H + h] = si;
}

template <int CIN, int H>
__global__ void k_node_dots(const float* __restrict__ xin, const float* __restrict__ waj,
                            const float* __restrict__ wai, float* __restrict__ ajd,
                            float* __restrict__ aid, int N) {
  int n = blockIdx.x * blockDim.x + threadIdx.x;
  if (n >= N) return;
  float sj[H], si[H];
#pragma unroll
  for (int h = 0; h < H; ++h) { sj[h] = 0.f; si[h] = 0.f; }
  const float* xr = xin + (size_t)n * CIN;
#pragma unroll 4
  for (int k = 0; k < CIN; ++k) {
    float xv = xr[k];
#pragma unroll
    for (int h = 0; h < H; ++h) {
      sj[h] = fmaf(xv, waj[k * H + h], sj[h]);
      si[h] = fmaf(xv, wai[k * H + h], si[h]);
    }
  }
#pragma unroll
  for (int h = 0; h < H; ++h) {
    ajd[(size_t)n * H + h] = sj[h];
    aid[(size_t)n * H + h] = si[h];
  }
}

// ---------------- per-node projection GEMM with fused att-dots (layers 0,1) ----------------
// xh[n,j] = sum_k xin[n,k] * W[k,j]   (64 output cols, lane j owns col j)
// ajd[n]  = sum_j xh[n,j] * att[j] ;  aid[n] = sum_j xh[n,j] * att[64+j]
template <int F>
__global__ __launch_bounds__(256) void k_gemm_nh(
    const float* __restrict__ xin, const float* __restrict__ W,
    const float* __restrict__ att, float* __restrict__ xh,
    float* __restrict__ ajd, float* __restrict__ aid, int N) {
  const int wave = threadIdx.x >> 6, lane = threadIdx.x & 63;
  float w[F];
#pragma unroll
  for (int k = 0; k < F; ++k) w[k] = W[k * 64 + lane];
  const float aj = att[lane], ai = att[64 + lane];
  for (int n = blockIdx.x * 4 + wave; n < N; n += gridDim.x * 4) {
    const float* xr = xin + (size_t)n * F;
    float a = 0.f;
#pragma unroll
    for (int k = 0; k < F; ++k) a = fmaf(xr[k], w[k], a);
    xh[(size_t)n * 64 + lane] = a;
    float sj = a * aj, si = a * ai;
#pragma unroll
    for (int o = 32; o > 0; o >>= 1) {
      sj += __shfl_xor(sj, o, 64);
      si += __shfl_xor(si, o, 64);
    }
    if (lane == 0) { ajd[n] = sj; aid[n] = si; }
  }
}

// ---------------- bf16 split helpers ----------------

__device__ __forceinline__ unsigned short bf16_rne(float x) {
  unsigned int u = __float_as_uint(x);
  return (unsigned short)((u + 0x7FFFu + ((u >> 16) & 1u)) >> 16);
}

// ---------------- MFMA-based edge scalar ep ----------------

// Build weight fragments (A-operand of the swapped MFMA).
// Concat weight matrix We_cat: 16 x 384 (cols 0-63 We0, 64-127 We1, 128-383 We2).
// Split f32 = hi + lo (bf16 each). K=32 arrangement matches the edge fragments:
// k<16 pairs with edge-hi, k>=16 pairs with edge-lo. B1 = [Whi;Whi], B2 = [Wlo;0].
// Fragment layout (operand-symmetric): lane l holds row/col = T*16 + (l&15),
// k = (l>>4)*8 + j, j=0..7.  avec[384]: a_p coefficient per concat column.
__global__ void k_prep_b(const float* __restrict__ We0, const float* __restrict__ We1,
                         const float* __restrict__ We2,
                         const float* __restrict__ att0, const float* __restrict__ att1,
                         const float* __restrict__ att2,
                         bf16x8* __restrict__ B1, bf16x8* __restrict__ B2,
                         float* __restrict__ avec) {
  int i = blockIdx.x * blockDim.x + threadIdx.x;
  if (i < 24 * 64) {
    int T = i >> 6, l = i & 63;
    int col = T * 16 + (l & 15);
    int grp = l >> 4;
    bf16x8 b1, b2;
#pragma unroll
    for (int j = 0; j < 8; ++j) {
      int kk = grp * 8 + j;     // 0..31
      int ks = kk & 15;         // source k (both halves use same Whi)
      float w;
      if (col < 64)        w = We0[ks * 64 + col];
      else if (col < 128)  w = We1[ks * 64 + (col - 64)];
      else                 w = We2[ks * 256 + (col - 128)];
      unsigned short hi = bf16_rne(w);
      float hif = __uint_as_float((unsigned int)hi << 16);
      unsigned short lo = bf16_rne(w - hif);
      b1[j] = (short)hi;
      b2[j] = (kk < 16) ? (short)lo : (short)0;
    }
    B1[i] = b1;
    B2[i] = b2;
  } else if (i < 24 * 64 + 384) {
    int col = i - 24 * 64;
    float a;
    if (col < 64)        a = att0[128 + col];
    else if (col < 128)  a = att1[128 + (col - 64)];
    else {
      int c = col - 128;
      a = att2[(c >> 6) * 192 + 128 + (c & 63)];
    }
    avec[col] = a;
  }
}

// One wave = 64 edges (4 edge fragments of 16, used as the MFMA *B* operand).
// A operand = weight tiles (d-outputs on the M side). D tile: col(lane&15)=edge,
// row(grp*4+reg)=d. The relu*a_p reduction over d is therefore in-register
// (4 FMAs/tile) + one 2-stage cross-group shfl per (seg,frag). ep2 accumulates
// in a float4 across segs 2-5 and stores once.
__global__ __launch_bounds__(256) void k_ep_mfma(
    const float* __restrict__ ea, const bf16x8* __restrict__ B1,
    const bf16x8* __restrict__ B2, const float* __restrict__ avec,
    const int* __restrict__ pos, float* __restrict__ ep0,
    float* __restrict__ ep1, float* __restrict__ ep2, int E) {
  const int lane = threadIdx.x & 63;
  const int wv = threadIdx.x >> 6;
  const long e0 = ((long)blockIdx.x * 4 + wv) * 64;
  const int grp = lane >> 4;        // 0..3
  const int row = lane & 15;        // edge index within fragment (B: N-col)
  const int kc = (grp & 1) * 8;     // which 8 source-k's this lane group loads
  const bool lo_grp = grp >= 2;     // groups 2,3 carry the lo halves (k 16..31)

  // ---- edge fragments (B operand) ----
  bf16x8 Bf[4];
#pragma unroll
  for (int f = 0; f < 4; ++f) {
    long e = e0 + f * 16 + row;
    if (e >= E) e = E - 1;          // clamp; stores guarded later
    const float* ar = ea + e * 16 + kc;
    float4 u0 = *reinterpret_cast<const float4*>(ar);
    float4 u1 = *reinterpret_cast<const float4*>(ar + 4);
    float v0 = u0.x, v1 = u0.y, v2 = u0.z, v3 = u0.w;
    float v4 = u1.x, v5 = u1.y, v6 = u1.z, v7 = u1.w;
    bf16x8 a;
#define CVT(J, V)                                                        \
    {                                                                    \
      unsigned short hi = bf16_rne(V);                                   \
      float hif = __uint_as_float((unsigned int)hi << 16);               \
      unsigned short lo = bf16_rne((V) - hif);                           \
      a[J] = (short)(lo_grp ? lo : hi);                                  \
    }
    CVT(0, v0) CVT(1, v1) CVT(2, v2) CVT(3, v3)
    CVT(4, v4) CVT(5, v5) CVT(6, v6) CVT(7, v7)
#undef CVT
    Bf[f] = a;
  }

  // ---- CSR positions (hoisted; used by lanes 0..15) ----
  int pf[4];
#pragma unroll
  for (int f = 0; f < 4; ++f) {
    long e = e0 + f * 16 + row;
    pf[f] = pos[e < E ? e : (E - 1)];
  }

  float4 v2acc[4];

  // ---- 6 segments x 4 tiles, d on the M (row) side ----
#pragma unroll
  for (int seg = 0; seg < 6; ++seg) {
    float sp0 = 0.f, sp1 = 0.f, sp2 = 0.f, sp3 = 0.f;
#pragma unroll
    for (int tt = 0; tt < 4; ++tt) {
      const int T = seg * 4 + tt;
      bf16x8 a1 = B1[T * 64 + lane];
      bf16x8 a2 = B2[T * 64 + lane];
      // a_p values for this lane's 4 d-rows: d = T*16 + grp*4 + r
      float4 av = *reinterpret_cast<const float4*>(avec + T * 16 + (grp << 2));
#define EPTILE(SP, F)                                                     \
      {                                                                   \
        f32x4 acc = {0.f, 0.f, 0.f, 0.f};                                 \
        acc = __builtin_amdgcn_mfma_f32_16x16x32_bf16(a1, Bf[F], acc, 0, 0, 0); \
        acc = __builtin_amdgcn_mfma_f32_16x16x32_bf16(a2, Bf[F], acc, 0, 0, 0); \
        SP = fmaf(fmaxf(acc[0], 0.f), av.x, SP);                          \
        SP = fmaf(fmaxf(acc[1], 0.f), av.y, SP);                          \
        SP = fmaf(fmaxf(acc[2], 0.f), av.z, SP);                          \
        SP = fmaf(fmaxf(acc[3], 0.f), av.w, SP);                          \
      }
      EPTILE(sp0, 0) EPTILE(sp1, 1) EPTILE(sp2, 2) EPTILE(sp3, 3)
#undef EPTILE
    }
    // combine the 4 lane-groups (each holds a quarter of the 64 d's)
    sp0 += __shfl_xor(sp0, 16, 64); sp0 += __shfl_xor(sp0, 32, 64);
    sp1 += __shfl_xor(sp1, 16, 64); sp1 += __shfl_xor(sp1, 32, 64);
    sp2 += __shfl_xor(sp2, 16, 64); sp2 += __shfl_xor(sp2, 32, 64);
    sp3 += __shfl_xor(sp3, 16, 64); sp3 += __shfl_xor(sp3, 32, 64);

    float spf[4] = {sp0, sp1, sp2, sp3};
    if (seg == 0) {
      if (lane < 16) {
#pragma unroll
        for (int f = 0; f < 4; ++f)
          if (e0 + f * 16 + lane < E) ep0[pf[f]] = spf[f];
      }
    } else if (seg == 1) {
      if (lane < 16) {
#pragma unroll
        for (int f = 0; f < 4; ++f)
          if (e0 + f * 16 + lane < E) ep1[pf[f]] = spf[f];
      }
    } else {
#pragma unroll
      for (int f = 0; f < 4; ++f) {
        if (seg == 2) v2acc[f].x = spf[f];
        if (seg == 3) v2acc[f].y = spf[f];
        if (seg == 4) v2acc[f].z = spf[f];
        if (seg == 5) v2acc[f].w = spf[f];
      }
    }
  }
  if (lane < 16) {
#pragma unroll
    for (int f = 0; f < 4; ++f)
      if (e0 + f * 16 + lane < E)
        reinterpret_cast<float4*>(ep2)[pf[f]] = v2acc[f];
  }
}

// ---------------- MFMA post GEMM (layer 2) ----------------

// W2 fragments: 16 global col-tiles (T: 256 cols / 16) x 4 k-chunks (c: K=64/16).
// Frag index (T*4+c)*64 + lane. Same split scheme as k_prep_b: slot kk=(l>>4)*8+j,
// C1 slot = Whi(k = c*16 + (kk&15)), C2 slot = (kk<16) ? Wlo : 0.
__global__ void k_prep_w2(const float* __restrict__ W2,
                          bf16x8* __restrict__ C1, bf16x8* __restrict__ C2) {
  int i = blockIdx.x * blockDim.x + threadIdx.x;
  if (i >= 16 * 4 * 64) return;
  int l = i & 63;
  int c = (i >> 6) & 3;
  int T = i >> 8;
  int col = T * 16 + (l & 15);
  int g = l >> 4;
  bf16x8 b1, b2;
#pragma unroll
  for (int j = 0; j < 8; ++j) {
    int kk = g * 8 + j;
    int ks = kk & 15;
    float w = W2[(size_t)(c * 16 + ks) * 256 + col];
    unsigned short hi = bf16_rne(w);
    float hif = __uint_as_float((unsigned int)hi << 16);
    unsigned short lo = bf16_rne(w - hif);
    b1[j] = (short)hi;
    b2[j] = (kk < 16) ? (short)lo : (short)0;
  }
  C1[i] = b1;
  C2[i] = b2;
}

// out[n, col] = sum_k agg[n, (col>>6)*64 + k] * W2[k, col]
// One wave = 16 nodes. A = agg rows (M side), B = W2 fragments (N side).
// D layout (m89): col = lane&15 (output col within tile), row = grp*4+reg (node).
// 32 independent float4 A-loads issued upfront -> no per-node latency chain.
__global__ __launch_bounds__(256) void k_post_mfma(
    const float* __restrict__ agg, const bf16x8* __restrict__ C1,
    const bf16x8* __restrict__ C2, float* __restrict__ out, int N) {
  const int lane = threadIdx.x & 63;
  const int wv = threadIdx.x >> 6;
  const int task = blockIdx.x * 4 + wv;
  const int ntask = (N + 15) / 16;
  if (task >= ntask) return;
  const int n0 = task * 16;
  const int g = lane >> 4;
  const int r = lane & 15;
  const int kc = (g & 1) * 8;
  const bool lo_grp = g >= 2;
  const int nrow = min(n0 + r, N - 1);   // clamp; stores guarded

  // ---- A fragments: [head][chunk], 8 agg values each ----
  bf16x8 A[4][4];
#pragma unroll
  for (int h = 0; h < 4; ++h)
#pragma unroll
    for (int c = 0; c < 4; ++c) {
      const float* ar = agg + (size_t)nrow * 256 + h * 64 + c * 16 + kc;
      float4 u0 = *reinterpret_cast<const float4*>(ar);
      float4 u1 = *reinterpret_cast<const float4*>(ar + 4);
      float v0 = u0.x, v1 = u0.y, v2 = u0.z, v3 = u0.w;
      float v4 = u1.x, v5 = u1.y, v6 = u1.z, v7 = u1.w;
      bf16x8 a;
#define CVT(J, V)                                                        \
      {                                                                  \
        unsigned short hi = bf16_rne(V);                                 \
        float hif = __uint_as_float((unsigned int)hi << 16);             \
        unsigned short lo = bf16_rne((V) - hif);                         \
        a[J] = (short)(lo_grp ? lo : hi);                                \
      }
      CVT(0, v0) CVT(1, v1) CVT(2, v2) CVT(3, v3)
      CVT(4, v4) CVT(5, v5) CVT(6, v6) CVT(7, v7)
#undef CVT
      A[h][c] = a;
    }

  // ---- 16 col-tiles: K-accumulate over 4 chunks x 2 MFMAs ----
#pragma unroll
  for (int T = 0; T < 16; ++T) {
    const int h = T >> 2;
    f32x4 acc = {0.f, 0.f, 0.f, 0.f};
#pragma unroll
    for (int c = 0; c < 4; ++c) {
      bf16x8 b1 = C1[(T * 4 + c) * 64 + lane];
      bf16x8 b2 = C2[(T * 4 + c) * 64 + lane];
      acc = __builtin_amdgcn_mfma_f32_16x16x32_bf16(A[h][c], b1, acc, 0, 0, 0);
      acc = __builtin_amdgcn_mfma_f32_16x16x32_bf16(A[h][c], b2, acc, 0, 0, 0);
    }
#pragma unroll
    for (int q = 0; q < 4; ++q) {
      int n = n0 + g * 4 + q;
      if (n < N) out[(size_t)n * 256 + T * 16 + r] = acc[q];
    }
  }
}

// ---------------- fused attention softmax + aggregate ----------------

template <int H>
__device__ __forceinline__ void loadH(const float* __restrict__ p, float* v) {
  if constexpr (H == 4) {
    float4 t = *reinterpret_cast<const float4*>(p);
    v[0] = t.x; v[1] = t.y; v[2] = t.z; v[3] = t.w;
  } else {
    v[0] = *p;
  }
}

// one wave per node, all H heads together.
// agg[n, h*F + f] = sum_e alpha_{e,h} * hin[src_e, f]   (+ optional ELU)
template <int F, int H, bool ELU_OUT>
__global__ __launch_bounds__(256) void k_attn_agg(
    const int* __restrict__ off, const int* __restrict__ ssrc,
    const float* __restrict__ hin, const float* __restrict__ ajd,
    const float* __restrict__ aid, const float* __restrict__ ep,
    float* __restrict__ outbuf, int N) {
  constexpr int FPL = F / 64;
  __shared__ float ls_alpha[4][64 * H];
  __shared__ int ls_src[4][64];
  const int wave = threadIdx.x >> 6, lane = threadIdx.x & 63;
  float* const la = ls_alpha[wave];
  int* const lsrc = ls_src[wave];

  for (int n = blockIdx.x * 4 + wave; n < N; n += gridDim.x * 4) {
    const int o0 = off[n];
    const int deg = off[n + 1] - o0;
    float aidn[H];
    loadH<H>(aid + (size_t)n * H, aidn);

    // ---- pass 1: online softmax stats (lane-parallel over edges) ----
    float m[H], s[H];
#pragma unroll
    for (int h = 0; h < H; ++h) { m[h] = -1e30f; s[h] = 0.f; }
    for (int i = lane; i < deg; i += 64) {
      int sr = ssrc[o0 + i];
      float aj[H], pv[H];
      loadH<H>(ajd + (size_t)sr * H, aj);
      loadH<H>(ep + (size_t)(o0 + i) * H, pv);
#pragma unroll
      for (int h = 0; h < H; ++h) {
        float sc = aj[h] + aidn[h] + pv[h];
        sc = sc > 0.f ? sc : 0.2f * sc;
        float mn = fmaxf(m[h], sc);
        s[h] = s[h] * __expf(m[h] - mn) + __expf(sc - mn);
        m[h] = mn;
      }
    }
#pragma unroll
    for (int o = 32; o > 0; o >>= 1) {
#pragma unroll
      for (int h = 0; h < H; ++h) {
        float m2 = __shfl_xor(m[h], o, 64);
        float s2 = __shfl_xor(s[h], o, 64);
        float mn = fmaxf(m[h], m2);
        s[h] = s[h] * __expf(m[h] - mn) + s2 * __expf(m2 - mn);
        m[h] = mn;
      }
    }
    float inv[H];
#pragma unroll
    for (int h = 0; h < H; ++h) inv[h] = 1.f / (s[h] + 1e-16f);

    // ---- pass 2: chunked alpha -> LDS, then 4-way unrolled gather+FMA ----
    float acc[H][FPL];
#pragma unroll
    for (int h = 0; h < H; ++h)
#pragma unroll
      for (int c = 0; c < FPL; ++c) acc[h][c] = 0.f;

    for (int base = 0; base < deg; base += 64) {
      const int cnt = min(64, deg - base);
      if (lane < cnt) {
        int i = base + lane;
        int sr = ssrc[o0 + i];
        lsrc[lane] = sr;
        float aj[H], pv[H];
        loadH<H>(ajd + (size_t)sr * H, aj);
        loadH<H>(ep + (size_t)(o0 + i) * H, pv);
#pragma unroll
        for (int h = 0; h < H; ++h) {
          float sc = aj[h] + aidn[h] + pv[h];
          sc = sc > 0.f ? sc : 0.2f * sc;
          la[lane * H + h] = __expf(sc - m[h]) * inv[h];
        }
      }
      asm volatile("s_waitcnt lgkmcnt(0)" ::: "memory");

      int j = 0;
      for (; j + 4 <= cnt; j += 4) {
        int srj[4];
        float av[4][H];
#pragma unroll
        for (int u = 0; u < 4; ++u) {
          srj[u] = lsrc[j + u];
          loadH<H>(la + (j + u) * H, av[u]);
        }
        float v[4][FPL];
#pragma unroll
        for (int u = 0; u < 4; ++u) {
          const float* hr = hin + (size_t)srj[u] * F + lane;
#pragma unroll
          for (int c = 0; c < FPL; ++c) v[u][c] = hr[c * 64];
        }
#pragma unroll
        for (int u = 0; u < 4; ++u)
#pragma unroll
          for (int h = 0; h < H; ++h)
#pragma unroll
            for (int c = 0; c < FPL; ++c)
              acc[h][c] = fmaf(av[u][h], v[u][c], acc[h][c]);
      }
      for (; j < cnt; ++j) {
        int sr = lsrc[j];
        float av[H];
        loadH<H>(la + j * H, av);
        const float* hr = hin + (size_t)sr * F + lane;
#pragma unroll
        for (int h = 0; h < H; ++h)
#pragma unroll
          for (int c = 0; c < FPL; ++c)
            acc[h][c] = fmaf(av[h], hr[c * 64], acc[h][c]);
      }
    }

    float* ob = outbuf + (size_t)n * (H * F);
#pragma unroll
    for (int h = 0; h < H; ++h)
#pragma unroll
      for (int c = 0; c < FPL; ++c) {
        float v = acc[h][c];
        if (ELU_OUT) v = (v > 0.f) ? v : expm1f(v);
        ob[h * F + c * 64 + lane] = v;
      }
  }
}

// ---------------- launch ----------------

extern "C" void kernel_launch(void* const* d_in, const int* in_sizes, int n_in,
                              void* d_out, int out_size, void* d_ws, size_t ws_size,
                              hipStream_t stream) {
  const float* x    = (const float*)d_in[0];
  const int*   ei   = (const int*)d_in[1];
  const float* ea   = (const float*)d_in[2];
  const float* W0   = (const float*)d_in[3];
  const float* We0  = (const float*)d_in[4];
  const float* att0 = (const float*)d_in[5];
  const float* W1   = (const float*)d_in[6];
  const float* We1  = (const float*)d_in[7];
  const float* att1 = (const float*)d_in[8];
  const float* W2   = (const float*)d_in[9];
  const float* We2  = (const float*)d_in[10];
  const float* att2 = (const float*)d_in[11];
  float* out = (float*)d_out;

  const int N = in_sizes[0] / 128;   // 50000
  const int E = in_sizes[2] / 16;    // 800000

  char* p = (char*)d_ws;
  auto alloc = [&](size_t bytes) {
    char* r = p;
    p += (bytes + 255) & ~(size_t)255;
    return r;
  };
  int*   flag = (int*)  alloc(sizeof(int));
  int*   off  = (int*)  alloc((size_t)(N + 1) * sizeof(int));
  int*   cur  = (int*)  alloc((size_t)N * sizeof(int));
  int*   pos  = (int*)  alloc((size_t)E * sizeof(int));
  int*   ssrc = (int*)  alloc((size_t)E * sizeof(int));
  bf16x8* B1  = (bf16x8*)alloc(24 * 64 * sizeof(bf16x8));
  bf16x8* B2  = (bf16x8*)alloc(24 * 64 * sizeof(bf16x8));
  bf16x8* C1  = (bf16x8*)alloc(64 * 64 * sizeof(bf16x8));
  bf16x8* C2  = (bf16x8*)alloc(64 * 64 * sizeof(bf16x8));
  float* avec = (float*)alloc(384 * sizeof(float));
  float* waj2 = (float*)alloc(256 * sizeof(float));
  float* wai2 = (float*)alloc(256 * sizeof(float));
  float* ajdA = (float*)alloc((size_t)N * sizeof(float));
  float* aidA = (float*)alloc((size_t)N * sizeof(float));
  float* ajd2 = (float*)alloc((size_t)N * 4 * sizeof(float));
  float* aid2 = (float*)alloc((size_t)N * 4 * sizeof(float));
  float* ep0  = (float*)alloc((size_t)E * sizeof(float));
  float* ep1  = (float*)alloc((size_t)E * sizeof(float));
  float* ep2  = (float*)alloc((size_t)E * 4 * sizeof(float));
  float* xh0  = (float*)alloc((size_t)N * 64 * sizeof(float));
  float* h1   = (float*)alloc((size_t)N * 64 * sizeof(float));
  float* xh1  = (float*)alloc((size_t)N * 64 * sizeof(float));
  float* h2   = (float*)alloc((size_t)N * 64 * sizeof(float));
  float* aggL2= (float*)alloc((size_t)N * 256 * sizeof(float));

  const int eb = (E + THR - 1) / THR;
  const int nb = (N + THR - 1) / THR;
  const int ab = (N + 3) / 4;
  const int gb = min(ab, 2048);
  const int pb = ((N + 15) / 16 + 3) / 4;   // post-MFMA: 4 wave-tasks of 16 nodes per block

  hipMemsetAsync(flag, 0, sizeof(int), stream);
  hipMemsetAsync(cur, 0, (size_t)N * sizeof(int), stream);

  k_detect<<<16, THR, 0, stream>>>(ei, flag);
  k_count<<<eb, THR, 0, stream>>>(ei, flag, cur, E);
  k_scan<<<1, 1024, 0, stream>>>(cur, off, N);
  k_scatter<<<eb, THR, 0, stream>>>(ei, flag, cur, pos, ssrc, E);

  k_prep_b<<<8, THR, 0, stream>>>(We0, We1, We2, att0, att1, att2, B1, B2, avec);
  k_prep_w2<<<16, THR, 0, stream>>>(W2, C1, C2);
  // 256 edges per block (4 waves x 64 edges)
  k_ep_mfma<<<(E + 255) / 256, THR, 0, stream>>>(ea, B1, B2, avec, pos,
                                                 ep0, ep1, ep2, E);

  // layer 0: xh0 = x@W0 (+ fused a_j/a_i dots), aggregate in output space, ELU fused
  k_gemm_nh<128><<<gb, THR, 0, stream>>>(x, W0, att0, xh0, ajdA, aidA, N);
  k_attn_agg<64, 1, true><<<ab, THR, 0, stream>>>(off, ssrc, xh0, ajdA, aidA, ep0, h1, N);

  // layer 1: xh1 = h1@W1, aggregate, ELU fused
  k_gemm_nh<64><<<gb, THR, 0, stream>>>(h1, W1, att1, xh1, ajdA, aidA, N);
  k_attn_agg<64, 1, true><<<ab, THR, 0, stream>>>(off, ssrc, xh1, ajdA, aidA, ep1, h2, N);

  // layer 2: input-space aggregation (64 < 4*64), then MFMA post GEMM
  k_fold_att<<<1, 256, 0, stream>>>(W2, att2, waj2, wai2, 64, 4);
  k_node_dots<64, 4><<<nb, THR, 0, stream>>>(h2, waj2, wai2, ajd2, aid2, N);
  k_attn_agg<64, 4, false><<<ab, THR, 0, stream>>>(off, ssrc, h2, ajd2, aid2, ep2, aggL2, N);
  k_post_mfma<<<pb, THR, 0, stream>>>(aggL2, C1, C2, out, N);
}

// Round 15
// 473.071 us; speedup vs baseline: 1.4249x; 1.2148x over previous
//
#include <hip/hip_runtime.h>
#include <math.h>

#define THR 256

typedef __attribute__((ext_vector_type(8))) short bf16x8;
typedef __attribute__((ext_vector_type(4))) float f32x4;

// ---------------- CSR build ----------------

// Detect whether edge_index buffer is int64 (high words all zero) or int32.
__global__ void k_detect(const int* __restrict__ w, int* __restrict__ flag) {
  int i = blockIdx.x * blockDim.x + threadIdx.x;
  if (i < 4096) {
    if (w[2 * i + 1] != 0) atomicOr(flag, 1);
  }
}

__device__ __forceinline__ int load_idx(const int* __restrict__ w, int pos, int is32) {
  return is32 ? w[pos] : w[2 * pos];
}

__global__ void k_count(const int* __restrict__ ei, const int* __restrict__ flag,
                        int* __restrict__ cnt, int E) {
  int e = blockIdx.x * blockDim.x + threadIdx.x;
  if (e < E) {
    int is32 = *flag;
    int d = load_idx(ei, E + e, is32);
    atomicAdd(&cnt[d], 1);
  }
}

// ---- 3-phase multi-block exclusive scan (replaces the 1-block k_scan) ----
// Phase 1: per-block exclusive scan of cnt -> off (block-local), bsum[b]=block total
__global__ __launch_bounds__(256) void k_scan1(const int* __restrict__ cnt,
                                               int* __restrict__ off,
                                               int* __restrict__ bsum, int n) {
  __shared__ int sm[256];
  const int t = threadIdx.x;
  const int i = blockIdx.x * 256 + t;
  int v = (i < n) ? cnt[i] : 0;
  sm[t] = v;
  __syncthreads();
  for (int d = 1; d < 256; d <<= 1) {
    int w = (t >= d) ? sm[t - d] : 0;
    __syncthreads();
    sm[t] += w;
    __syncthreads();
  }
  if (i < n) off[i] = sm[t] - v;       // exclusive within block
  if (t == 255) bsum[blockIdx.x] = sm[255];
}

// Phase 2: single block scans the block sums (nb <= 256); writes off[n] = total
__global__ __launch_bounds__(256) void k_scan2(const int* __restrict__ bsum,
                                               int* __restrict__ boff,
                                               int* __restrict__ off, int nb, int n) {
  __shared__ int sm[256];
  const int t = threadIdx.x;
  int v = (t < nb) ? bsum[t] : 0;
  sm[t] = v;
  __syncthreads();
  for (int d = 1; d < 256; d <<= 1) {
    int w = (t >= d) ? sm[t - d] : 0;
    __syncthreads();
    sm[t] += w;
    __syncthreads();
  }
  if (t < nb) boff[t] = sm[t] - v;
  if (t == 255) off[n] = sm[255];
}

// Phase 3: add block offsets; produce final off and cursor copy
__global__ __launch_bounds__(256) void k_scan3(int* __restrict__ off,
                                               const int* __restrict__ boff,
                                               int* __restrict__ cur, int n) {
  const int i = blockIdx.x * 256 + threadIdx.x;
  if (i < n) {
    int o = off[i] + boff[blockIdx.x];
    off[i] = o;
    cur[i] = o;
  }
}

__global__ void k_scatter(const int* __restrict__ ei, const int* __restrict__ flag,
                          int* __restrict__ cur, int* __restrict__ pos,
                          int* __restrict__ ssrc, int E) {
  int e = blockIdx.x * blockDim.x + threadIdx.x;
  if (e < E) {
    int is32 = *flag;
    int d = load_idx(ei, E + e, is32);
    int s = load_idx(ei, e, is32);
    int p = atomicAdd(&cur[d], 1);
    pos[e] = p;
    ssrc[p] = s;
  }
}

// ---------------- weight prep (layer 2 only) ----------------

__global__ void k_fold_att(const float* __restrict__ W, const float* __restrict__ att,
                           float* __restrict__ waj, float* __restrict__ wai,
                           int Cin, int H) {
  int i = blockIdx.x * blockDim.x + threadIdx.x;
  if (i >= Cin * H) return;
  int k = i / H, h = i % H;
  float sj = 0.f, si = 0.f;
  for (int d = 0; d < 64; ++d) {
    float w = W[k * (H * 64) + h * 64 + d];
    sj = fmaf(w, att[h * 192 + d], sj);
    si = fmaf(w, att[h * 192 + 64 + d], si);
  }
  waj[k * H + h] = sj;
  wai[k * H + h] = si;
}

template <int CIN, int H>
__global__ void k_node_dots(const float* __restrict__ xin, const float* __restrict__ waj,
                            const float* __restrict__ wai, float* __restrict__ ajd,
                            float* __restrict__ aid, int N) {
  int n = blockIdx.x * blockDim.x + threadIdx.x;
  if (n >= N) return;
  float sj[H], si[H];
#pragma unroll
  for (int h = 0; h < H; ++h) { sj[h] = 0.f; si[h] = 0.f; }
  const float* xr = xin + (size_t)n * CIN;
#pragma unroll 4
  for (int k = 0; k < CIN; ++k) {
    float xv = xr[k];
#pragma unroll
    for (int h = 0; h < H; ++h) {
      sj[h] = fmaf(xv, waj[k * H + h], sj[h]);
      si[h] = fmaf(xv, wai[k * H + h], si[h]);
    }
  }
#pragma unroll
  for (int h = 0; h < H; ++h) {
    ajd[(size_t)n * H + h] = sj[h];
    aid[(size_t)n * H + h] = si[h];
  }
}

// ---------------- per-node projection GEMM with fused att-dots (layers 0,1) ----------------
// xh[n,j] = sum_k xin[n,k] * W[k,j]   (64 output cols, lane j owns col j)
// ajd[n]  = sum_j xh[n,j] * att[j] ;  aid[n] = sum_j xh[n,j] * att[64+j]
template <int F>
__global__ __launch_bounds__(256) void k_gemm_nh(
    const float* __restrict__ xin, const float* __restrict__ W,
    const float* __restrict__ att, float* __restrict__ xh,
    float* __restrict__ ajd, float* __restrict__ aid, int N) {
  const int wave = threadIdx.x >> 6, lane = threadIdx.x & 63;
  float w[F];
#pragma unroll
  for (int k = 0; k < F; ++k) w[k] = W[k * 64 + lane];
  const float aj = att[lane], ai = att[64 + lane];
  for (int n = blockIdx.x * 4 + wave; n < N; n += gridDim.x * 4) {
    const float* xr = xin + (size_t)n * F;
    float a = 0.f;
#pragma unroll
    for (int k = 0; k < F; ++k) a = fmaf(xr[k], w[k], a);
    xh[(size_t)n * 64 + lane] = a;
    float sj = a * aj, si = a * ai;
#pragma unroll
    for (int o = 32; o > 0; o >>= 1) {
      sj += __shfl_xor(sj, o, 64);
      si += __shfl_xor(si, o, 64);
    }
    if (lane == 0) { ajd[n] = sj; aid[n] = si; }
  }
}

// ---------------- bf16 split helpers ----------------

__device__ __forceinline__ unsigned short bf16_rne(float x) {
  unsigned int u = __float_as_uint(x);
  return (unsigned short)((u + 0x7FFFu + ((u >> 16) & 1u)) >> 16);
}

// ---------------- MFMA-based edge scalar ep ----------------

// Build weight fragments (A-operand of the swapped MFMA).
// Concat weight matrix We_cat: 16 x 384 (cols 0-63 We0, 64-127 We1, 128-383 We2).
// Split f32 = hi + lo (bf16 each). K=32 arrangement matches the edge fragments:
// k<16 pairs with edge-hi, k>=16 pairs with edge-lo. B1 = [Whi;Whi], B2 = [Wlo;0].
// Fragment layout (operand-symmetric): lane l holds row/col = T*16 + (l&15),
// k = (l>>4)*8 + j, j=0..7.  avec[384]: a_p coefficient per concat column.
__global__ void k_prep_b(const float* __restrict__ We0, const float* __restrict__ We1,
                         const float* __restrict__ We2,
                         const float* __restrict__ att0, const float* __restrict__ att1,
                         const float* __restrict__ att2,
                         bf16x8* __restrict__ B1, bf16x8* __restrict__ B2,
                         float* __restrict__ avec) {
  int i = blockIdx.x * blockDim.x + threadIdx.x;
  if (i < 24 * 64) {
    int T = i >> 6, l = i & 63;
    int col = T * 16 + (l & 15);
    int grp = l >> 4;
    bf16x8 b1, b2;
#pragma unroll
    for (int j = 0; j < 8; ++j) {
      int kk = grp * 8 + j;     // 0..31
      int ks = kk & 15;         // source k (both halves use same Whi)
      float w;
      if (col < 64)        w = We0[ks * 64 + col];
      else if (col < 128)  w = We1[ks * 64 + (col - 64)];
      else                 w = We2[ks * 256 + (col - 128)];
      unsigned short hi = bf16_rne(w);
      float hif = __uint_as_float((unsigned int)hi << 16);
      unsigned short lo = bf16_rne(w - hif);
      b1[j] = (short)hi;
      b2[j] = (kk < 16) ? (short)lo : (short)0;
    }
    B1[i] = b1;
    B2[i] = b2;
  } else if (i < 24 * 64 + 384) {
    int col = i - 24 * 64;
    float a;
    if (col < 64)        a = att0[128 + col];
    else if (col < 128)  a = att1[128 + (col - 64)];
    else {
      int c = col - 128;
      a = att2[(c >> 6) * 192 + 128 + (c & 63)];
    }
    avec[col] = a;
  }
}

// One wave = 64 edges (4 edge fragments of 16, used as the MFMA *B* operand).
// A operand = weight tiles (d-outputs on the M side). D tile: col(lane&15)=edge,
// row(grp*4+reg)=d. The relu*a_p reduction over d is therefore in-register
// (4 FMAs/tile) + one 2-stage cross-group shfl per (seg,frag). ep2 accumulates
// in a float4 across segs 2-5 and stores once.
__global__ __launch_bounds__(256) void k_ep_mfma(
    const float* __restrict__ ea, const bf16x8* __restrict__ B1,
    const bf16x8* __restrict__ B2, const float* __restrict__ avec,
    const int* __restrict__ pos, float* __restrict__ ep0,
    float* __restrict__ ep1, float* __restrict__ ep2, int E) {
  const int lane = threadIdx.x & 63;
  const int wv = threadIdx.x >> 6;
  const long e0 = ((long)blockIdx.x * 4 + wv) * 64;
  const int grp = lane >> 4;        // 0..3
  const int row = lane & 15;        // edge index within fragment (B: N-col)
  const int kc = (grp & 1) * 8;     // which 8 source-k's this lane group loads
  const bool lo_grp = grp >= 2;     // groups 2,3 carry the lo halves (k 16..31)

  // ---- edge fragments (B operand) ----
  bf16x8 Bf[4];
#pragma unroll
  for (int f = 0; f < 4; ++f) {
    long e = e0 + f * 16 + row;
    if (e >= E) e = E - 1;          // clamp; stores guarded later
    const float* ar = ea + e * 16 + kc;
    float4 u0 = *reinterpret_cast<const float4*>(ar);
    float4 u1 = *reinterpret_cast<const float4*>(ar + 4);
    float v0 = u0.x, v1 = u0.y, v2 = u0.z, v3 = u0.w;
    float v4 = u1.x, v5 = u1.y, v6 = u1.z, v7 = u1.w;
    bf16x8 a;
#define CVT(J, V)                                                        \
    {                                                                    \
      unsigned short hi = bf16_rne(V);                                   \
      float hif = __uint_as_float((unsigned int)hi << 16);               \
      unsigned short lo = bf16_rne((V) - hif);                           \
      a[J] = (short)(lo_grp ? lo : hi);                                  \
    }
    CVT(0, v0) CVT(1, v1) CVT(2, v2) CVT(3, v3)
    CVT(4, v4) CVT(5, v5) CVT(6, v6) CVT(7, v7)
#undef CVT
    Bf[f] = a;
  }

  // ---- CSR positions (hoisted; used by lanes 0..15) ----
  int pf[4];
#pragma unroll
  for (int f = 0; f < 4; ++f) {
    long e = e0 + f * 16 + row;
    pf[f] = pos[e < E ? e : (E - 1)];
  }

  float4 v2acc[4];

  // ---- 6 segments x 4 tiles, d on the M (row) side ----
#pragma unroll
  for (int seg = 0; seg < 6; ++seg) {
    float sp0 = 0.f, sp1 = 0.f, sp2 = 0.f, sp3 = 0.f;
#pragma unroll
    for (int tt = 0; tt < 4; ++tt) {
      const int T = seg * 4 + tt;
      bf16x8 a1 = B1[T * 64 + lane];
      bf16x8 a2 = B2[T * 64 + lane];
      // a_p values for this lane's 4 d-rows: d = T*16 + grp*4 + r
      float4 av = *reinterpret_cast<const float4*>(avec + T * 16 + (grp << 2));
#define EPTILE(SP, F)                                                     \
      {                                                                   \
        f32x4 acc = {0.f, 0.f, 0.f, 0.f};                                 \
        acc = __builtin_amdgcn_mfma_f32_16x16x32_bf16(a1, Bf[F], acc, 0, 0, 0); \
        acc = __builtin_amdgcn_mfma_f32_16x16x32_bf16(a2, Bf[F], acc, 0, 0, 0); \
        SP = fmaf(fmaxf(acc[0], 0.f), av.x, SP);                          \
        SP = fmaf(fmaxf(acc[1], 0.f), av.y, SP);                          \
        SP = fmaf(fmaxf(acc[2], 0.f), av.z, SP);                          \
        SP = fmaf(fmaxf(acc[3], 0.f), av.w, SP);                          \
      }
      EPTILE(sp0, 0) EPTILE(sp1, 1) EPTILE(sp2, 2) EPTILE(sp3, 3)
#undef EPTILE
    }
    // combine the 4 lane-groups (each holds a quarter of the 64 d's)
    sp0 += __shfl_xor(sp0, 16, 64); sp0 += __shfl_xor(sp0, 32, 64);
    sp1 += __shfl_xor(sp1, 16, 64); sp1 += __shfl_xor(sp1, 32, 64);
    sp2 += __shfl_xor(sp2, 16, 64); sp2 += __shfl_xor(sp2, 32, 64);
    sp3 += __shfl_xor(sp3, 16, 64); sp3 += __shfl_xor(sp3, 32, 64);

    float spf[4] = {sp0, sp1, sp2, sp3};
    if (seg == 0) {
      if (lane < 16) {
#pragma unroll
        for (int f = 0; f < 4; ++f)
          if (e0 + f * 16 + lane < E) ep0[pf[f]] = spf[f];
      }
    } else if (seg == 1) {
      if (lane < 16) {
#pragma unroll
        for (int f = 0; f < 4; ++f)
          if (e0 + f * 16 + lane < E) ep1[pf[f]] = spf[f];
      }
    } else {
#pragma unroll
      for (int f = 0; f < 4; ++f) {
        if (seg == 2) v2acc[f].x = spf[f];
        if (seg == 3) v2acc[f].y = spf[f];
        if (seg == 4) v2acc[f].z = spf[f];
        if (seg == 5) v2acc[f].w = spf[f];
      }
    }
  }
  if (lane < 16) {
#pragma unroll
    for (int f = 0; f < 4; ++f)
      if (e0 + f * 16 + lane < E)
        reinterpret_cast<float4*>(ep2)[pf[f]] = v2acc[f];
  }
}

// ---------------- MFMA post GEMM (layer 2) ----------------

// W2 fragments: 16 global col-tiles (T: 256 cols / 16) x 4 k-chunks (c: K=64/16).
// Frag index (T*4+c)*64 + lane. Same split scheme as k_prep_b: slot kk=(l>>4)*8+j,
// C1 slot = Whi(k = c*16 + (kk&15)), C2 slot = (kk<16) ? Wlo : 0.
__global__ void k_prep_w2(const float* __restrict__ W2,
                          bf16x8* __restrict__ C1, bf16x8* __restrict__ C2) {
  int i = blockIdx.x * blockDim.x + threadIdx.x;
  if (i >= 16 * 4 * 64) return;
  int l = i & 63;
  int c = (i >> 6) & 3;
  int T = i >> 8;
  int col = T * 16 + (l & 15);
  int g = l >> 4;
  bf16x8 b1, b2;
#pragma unroll
  for (int j = 0; j < 8; ++j) {
    int kk = g * 8 + j;
    int ks = kk & 15;
    float w = W2[(size_t)(c * 16 + ks) * 256 + col];
    unsigned short hi = bf16_rne(w);
    float hif = __uint_as_float((unsigned int)hi << 16);
    unsigned short lo = bf16_rne(w - hif);
    b1[j] = (short)hi;
    b2[j] = (kk < 16) ? (short)lo : (short)0;
  }
  C1[i] = b1;
  C2[i] = b2;
}

// out[n, col] = sum_k agg[n, (col>>6)*64 + k] * W2[k, col]
// One wave = 16 nodes. A = agg rows (M side), B = W2 fragments (N side).
// D layout (m89): col = lane&15 (output col within tile), row = grp*4+reg (node).
// 32 independent float4 A-loads issued upfront -> no per-node latency chain.
__global__ __launch_bounds__(256) void k_post_mfma(
    const float* __restrict__ agg, const bf16x8* __restrict__ C1,
    const bf16x8* __restrict__ C2, float* __restrict__ out, int N) {
  const int lane = threadIdx.x & 63;
  const int wv = threadIdx.x >> 6;
  const int task = blockIdx.x * 4 + wv;
  const int ntask = (N + 15) / 16;
  if (task >= ntask) return;
  const int n0 = task * 16;
  const int g = lane >> 4;
  const int r = lane & 15;
  const int kc = (g & 1) * 8;
  const bool lo_grp = g >= 2;
  const int nrow = min(n0 + r, N - 1);   // clamp; stores guarded

  // ---- A fragments: [head][chunk], 8 agg values each ----
  bf16x8 A[4][4];
#pragma unroll
  for (int h = 0; h < 4; ++h)
#pragma unroll
    for (int c = 0; c < 4; ++c) {
      const float* ar = agg + (size_t)nrow * 256 + h * 64 + c * 16 + kc;
      float4 u0 = *reinterpret_cast<const float4*>(ar);
      float4 u1 = *reinterpret_cast<const float4*>(ar + 4);
      float v0 = u0.x, v1 = u0.y, v2 = u0.z, v3 = u0.w;
      float v4 = u1.x, v5 = u1.y, v6 = u1.z, v7 = u1.w;
      bf16x8 a;
#define CVT(J, V)                                                        \
      {                                                                  \
        unsigned short hi = bf16_rne(V);                                 \
        float hif = __uint_as_float((unsigned int)hi << 16);             \
        unsigned short lo = bf16_rne((V) - hif);                         \
        a[J] = (short)(lo_grp ? lo : hi);                                \
      }
      CVT(0, v0) CVT(1, v1) CVT(2, v2) CVT(3, v3)
      CVT(4, v4) CVT(5, v5) CVT(6, v6) CVT(7, v7)
#undef CVT
      A[h][c] = a;
    }

  // ---- 16 col-tiles: K-accumulate over 4 chunks x 2 MFMAs ----
#pragma unroll
  for (int T = 0; T < 16; ++T) {
    const int h = T >> 2;
    f32x4 acc = {0.f, 0.f, 0.f, 0.f};
#pragma unroll
    for (int c = 0; c < 4; ++c) {
      bf16x8 b1 = C1[(T * 4 + c) * 64 + lane];
      bf16x8 b2 = C2[(T * 4 + c) * 64 + lane];
      acc = __builtin_amdgcn_mfma_f32_16x16x32_bf16(A[h][c], b1, acc, 0, 0, 0);
      acc = __builtin_amdgcn_mfma_f32_16x16x32_bf16(A[h][c], b2, acc, 0, 0, 0);
    }
#pragma unroll
    for (int q = 0; q < 4; ++q) {
      int n = n0 + g * 4 + q;
      if (n < N) out[(size_t)n * 256 + T * 16 + r] = acc[q];
    }
  }
}

// ---------------- fused attention softmax + aggregate ----------------

template <int H>
__device__ __forceinline__ void loadH(const float* __restrict__ p, float* v) {
  if constexpr (H == 4) {
    float4 t = *reinterpret_cast<const float4*>(p);
    v[0] = t.x; v[1] = t.y; v[2] = t.z; v[3] = t.w;
  } else {
    v[0] = *p;
  }
}

// one wave per node, all H heads together.
// agg[n, h*F + f] = sum_e alpha_{e,h} * hin[src_e, f]   (+ optional ELU)
template <int F, int H, bool ELU_OUT>
__global__ __launch_bounds__(256) void k_attn_agg(
    const int* __restrict__ off, const int* __restrict__ ssrc,
    const float* __restrict__ hin, const float* __restrict__ ajd,
    const float* __restrict__ aid, const float* __restrict__ ep,
    float* __restrict__ outbuf, int N) {
  constexpr int FPL = F / 64;
  __shared__ float ls_alpha[4][64 * H];
  __shared__ int ls_src[4][64];
  const int wave = threadIdx.x >> 6, lane = threadIdx.x & 63;
  float* const la = ls_alpha[wave];
  int* const lsrc = ls_src[wave];

  for (int n = blockIdx.x * 4 + wave; n < N; n += gridDim.x * 4) {
    const int o0 = off[n];
    const int deg = off[n + 1] - o0;
    float aidn[H];
    loadH<H>(aid + (size_t)n * H, aidn);

    // ---- pass 1: online softmax stats (lane-parallel over edges) ----
    float m[H], s[H];
#pragma unroll
    for (int h = 0; h < H; ++h) { m[h] = -1e30f; s[h] = 0.f; }
    for (int i = lane; i < deg; i += 64) {
      int sr = ssrc[o0 + i];
      float aj[H], pv[H];
      loadH<H>(ajd + (size_t)sr * H, aj);
      loadH<H>(ep + (size_t)(o0 + i) * H, pv);
#pragma unroll
      for (int h = 0; h < H; ++h) {
        float sc = aj[h] + aidn[h] + pv[h];
        sc = sc > 0.f ? sc : 0.2f * sc;
        float mn = fmaxf(m[h], sc);
        s[h] = s[h] * __expf(m[h] - mn) + __expf(sc - mn);
        m[h] = mn;
      }
    }
#pragma unroll
    for (int o = 32; o > 0; o >>= 1) {
#pragma unroll
      for (int h = 0; h < H; ++h) {
        float m2 = __shfl_xor(m[h], o, 64);
        float s2 = __shfl_xor(s[h], o, 64);
        float mn = fmaxf(m[h], m2);
        s[h] = s[h] * __expf(m[h] - mn) + s2 * __expf(m2 - mn);
        m[h] = mn;
      }
    }
    float inv[H];
#pragma unroll
    for (int h = 0; h < H; ++h) inv[h] = 1.f / (s[h] + 1e-16f);

    // ---- pass 2: chunked alpha -> LDS, then 4-way unrolled gather+FMA ----
    float acc[H][FPL];
#pragma unroll
    for (int h = 0; h < H; ++h)
#pragma unroll
      for (int c = 0; c < FPL; ++c) acc[h][c] = 0.f;

    for (int base = 0; base < deg; base += 64) {
      const int cnt = min(64, deg - base);
      if (lane < cnt) {
        int i = base + lane;
        int sr = ssrc[o0 + i];
        lsrc[lane] = sr;
        float aj[H], pv[H];
        loadH<H>(ajd + (size_t)sr * H, aj);
        loadH<H>(ep + (size_t)(o0 + i) * H, pv);
#pragma unroll
        for (int h = 0; h < H; ++h) {
          float sc = aj[h] + aidn[h] + pv[h];
          sc = sc > 0.f ? sc : 0.2f * sc;
          la[lane * H + h] = __expf(sc - m[h]) * inv[h];
        }
      }
      asm volatile("s_waitcnt lgkmcnt(0)" ::: "memory");

      int j = 0;
      for (; j + 4 <= cnt; j += 4) {
        int srj[4];
        float av[4][H];
#pragma unroll
        for (int u = 0; u < 4; ++u) {
          srj[u] = lsrc[j + u];
          loadH<H>(la + (j + u) * H, av[u]);
        }
        float v[4][FPL];
#pragma unroll
        for (int u = 0; u < 4; ++u) {
          const float* hr = hin + (size_t)srj[u] * F + lane;
#pragma unroll
          for (int c = 0; c < FPL; ++c) v[u][c] = hr[c * 64];
        }
#pragma unroll
        for (int u = 0; u < 4; ++u)
#pragma unroll
          for (int h = 0; h < H; ++h)
#pragma unroll
            for (int c = 0; c < FPL; ++c)
              acc[h][c] = fmaf(av[u][h], v[u][c], acc[h][c]);
      }
      for (; j < cnt; ++j) {
        int sr = lsrc[j];
        float av[H];
        loadH<H>(la + j * H, av);
        const float* hr = hin + (size_t)sr * F + lane;
#pragma unroll
        for (int h = 0; h < H; ++h)
#pragma unroll
          for (int c = 0; c < FPL; ++c)
            acc[h][c] = fmaf(av[h], hr[c * 64], acc[h][c]);
      }
    }

    float* ob = outbuf + (size_t)n * (H * F);
#pragma unroll
    for (int h = 0; h < H; ++h)
#pragma unroll
      for (int c = 0; c < FPL; ++c) {
        float v = acc[h][c];
        if (ELU_OUT) v = (v > 0.f) ? v : expm1f(v);
        ob[h * F + c * 64 + lane] = v;
      }
  }
}

// ---------------- launch ----------------

extern "C" void kernel_launch(void* const* d_in, const int* in_sizes, int n_in,
                              void* d_out, int out_size, void* d_ws, size_t ws_size,
                              hipStream_t stream) {
  const float* x    = (const float*)d_in[0];
  const int*   ei   = (const int*)d_in[1];
  const float* ea   = (const float*)d_in[2];
  const float* W0   = (const float*)d_in[3];
  const float* We0  = (const float*)d_in[4];
  const float* att0 = (const float*)d_in[5];
  const float* W1   = (const float*)d_in[6];
  const float* We1  = (const float*)d_in[7];
  const float* att1 = (const float*)d_in[8];
  const float* W2   = (const float*)d_in[9];
  const float* We2  = (const float*)d_in[10];
  const float* att2 = (const float*)d_in[11];
  float* out = (float*)d_out;

  const int N = in_sizes[0] / 128;   // 50000
  const int E = in_sizes[2] / 16;    // 800000

  char* p = (char*)d_ws;
  auto alloc = [&](size_t bytes) {
    char* r = p;
    p += (bytes + 255) & ~(size_t)255;
    return r;
  };
  int*   flag = (int*)  alloc(sizeof(int));
  int*   off  = (int*)  alloc((size_t)(N + 1) * sizeof(int));
  int*   cur  = (int*)  alloc((size_t)N * sizeof(int));
  int*   bsum = (int*)  alloc(256 * sizeof(int));
  int*   boff = (int*)  alloc(256 * sizeof(int));
  int*   pos  = (int*)  alloc((size_t)E * sizeof(int));
  int*   ssrc = (int*)  alloc((size_t)E * sizeof(int));
  bf16x8* B1  = (bf16x8*)alloc(24 * 64 * sizeof(bf16x8));
  bf16x8* B2  = (bf16x8*)alloc(24 * 64 * sizeof(bf16x8));
  bf16x8* C1  = (bf16x8*)alloc(64 * 64 * sizeof(bf16x8));
  bf16x8* C2  = (bf16x8*)alloc(64 * 64 * sizeof(bf16x8));
  float* avec = (float*)alloc(384 * sizeof(float));
  float* waj2 = (float*)alloc(256 * sizeof(float));
  float* wai2 = (float*)alloc(256 * sizeof(float));
  float* ajdA = (float*)alloc((size_t)N * sizeof(float));
  float* aidA = (float*)alloc((size_t)N * sizeof(float));
  float* ajd2 = (float*)alloc((size_t)N * 4 * sizeof(float));
  float* aid2 = (float*)alloc((size_t)N * 4 * sizeof(float));
  float* ep0  = (float*)alloc((size_t)E * sizeof(float));
  float* ep1  = (float*)alloc((size_t)E * sizeof(float));
  float* ep2  = (float*)alloc((size_t)E * 4 * sizeof(float));
  float* xh0  = (float*)alloc((size_t)N * 64 * sizeof(float));
  float* h1   = (float*)alloc((size_t)N * 64 * sizeof(float));
  float* xh1  = (float*)alloc((size_t)N * 64 * sizeof(float));
  float* h2   = (float*)alloc((size_t)N * 64 * sizeof(float));
  float* aggL2= (float*)alloc((size_t)N * 256 * sizeof(float));

  const int eb = (E + THR - 1) / THR;
  const int nb = (N + THR - 1) / THR;
  const int sb = (N + 255) / 256;           // scan blocks (196 <= 256)
  const int ab = (N + 3) / 4;
  const int gb = min(ab, 2048);
  const int pb = ((N + 15) / 16 + 3) / 4;   // post-MFMA: 4 wave-tasks of 16 nodes per block

  hipMemsetAsync(flag, 0, sizeof(int), stream);
  hipMemsetAsync(cur, 0, (size_t)N * sizeof(int), stream);

  k_detect<<<16, THR, 0, stream>>>(ei, flag);
  k_count<<<eb, THR, 0, stream>>>(ei, flag, cur, E);
  k_scan1<<<sb, 256, 0, stream>>>(cur, off, bsum, N);
  k_scan2<<<1, 256, 0, stream>>>(bsum, boff, off, sb, N);
  k_scan3<<<sb, 256, 0, stream>>>(off, boff, cur, N);
  k_scatter<<<eb, THR, 0, stream>>>(ei, flag, cur, pos, ssrc, E);

  k_prep_b<<<8, THR, 0, stream>>>(We0, We1, We2, att0, att1, att2, B1, B2, avec);
  k_prep_w2<<<16, THR, 0, stream>>>(W2, C1, C2);
  // 256 edges per block (4 waves x 64 edges)
  k_ep_mfma<<<(E + 255) / 256, THR, 0, stream>>>(ea, B1, B2, avec, pos,
                                                 ep0, ep1, ep2, E);

  // layer 0: xh0 = x@W0 (+ fused a_j/a_i dots), aggregate in output space, ELU fused
  k_gemm_nh<128><<<gb, THR, 0, stream>>>(x, W0, att0, xh0, ajdA, aidA, N);
  k_attn_agg<64, 1, true><<<ab, THR, 0, stream>>>(off, ssrc, xh0, ajdA, aidA, ep0, h1, N);

  // layer 1: xh1 = h1@W1, aggregate, ELU fused
  k_gemm_nh<64><<<gb, THR, 0, stream>>>(h1, W1, att1, xh1, ajdA, aidA, N);
  k_attn_agg<64, 1, true><<<ab, THR, 0, stream>>>(off, ssrc, xh1, ajdA, aidA, ep1, h2, N);

  // layer 2: input-space aggregation (64 < 4*64), then MFMA post GEMM
  k_fold_att<<<1, 256, 0, stream>>>(W2, att2, waj2, wai2, 64, 4);
  k_node_dots<64, 4><<<nb, THR, 0, stream>>>(h2, waj2, wai2, ajd2, aid2, N);
  k_attn_agg<64, 4, false><<<ab, THR, 0, stream>>>(off, ssrc, h2, ajd2, aid2, ep2, aggL2, N);
  k_post_mfma<<<pb, THR, 0, stream>>>(aggL2, C1, C2, out, N);
}

// Round 16
// 464.552 us; speedup vs baseline: 1.4510x; 1.0183x over previous
//
#include <hip/hip_runtime.h>
#include <math.h>

#define THR 256

typedef __attribute__((ext_vector_type(8))) short bf16x8;
typedef __attribute__((ext_vector_type(4))) float f32x4;

// ---------------- CSR build ----------------

// Detect whether edge_index buffer is int64 (high words all zero) or int32.
__global__ void k_detect(const int* __restrict__ w, int* __restrict__ flag) {
  int i = blockIdx.x * blockDim.x + threadIdx.x;
  if (i < 4096) {
    if (w[2 * i + 1] != 0) atomicOr(flag, 1);
  }
}

__device__ __forceinline__ int load_idx(const int* __restrict__ w, int pos, int is32) {
  return is32 ? w[pos] : w[2 * pos];
}

__global__ void k_count(const int* __restrict__ ei, const int* __restrict__ flag,
                        int* __restrict__ cnt, int E) {
  int e = blockIdx.x * blockDim.x + threadIdx.x;
  if (e < E) {
    int is32 = *flag;
    int d = load_idx(ei, E + e, is32);
    atomicAdd(&cnt[d], 1);
  }
}

// ---- 3-phase multi-block exclusive scan ----
__global__ __launch_bounds__(256) void k_scan1(const int* __restrict__ cnt,
                                               int* __restrict__ off,
                                               int* __restrict__ bsum, int n) {
  __shared__ int sm[256];
  const int t = threadIdx.x;
  const int i = blockIdx.x * 256 + t;
  int v = (i < n) ? cnt[i] : 0;
  sm[t] = v;
  __syncthreads();
  for (int d = 1; d < 256; d <<= 1) {
    int w = (t >= d) ? sm[t - d] : 0;
    __syncthreads();
    sm[t] += w;
    __syncthreads();
  }
  if (i < n) off[i] = sm[t] - v;       // exclusive within block
  if (t == 255) bsum[blockIdx.x] = sm[255];
}

__global__ __launch_bounds__(256) void k_scan2(const int* __restrict__ bsum,
                                               int* __restrict__ boff,
                                               int* __restrict__ off, int nb, int n) {
  __shared__ int sm[256];
  const int t = threadIdx.x;
  int v = (t < nb) ? bsum[t] : 0;
  sm[t] = v;
  __syncthreads();
  for (int d = 1; d < 256; d <<= 1) {
    int w = (t >= d) ? sm[t - d] : 0;
    __syncthreads();
    sm[t] += w;
    __syncthreads();
  }
  if (t < nb) boff[t] = sm[t] - v;
  if (t == 255) off[n] = sm[255];
}

__global__ __launch_bounds__(256) void k_scan3(int* __restrict__ off,
                                               const int* __restrict__ boff,
                                               int* __restrict__ cur, int n) {
  const int i = blockIdx.x * 256 + threadIdx.x;
  if (i < n) {
    int o = off[i] + boff[blockIdx.x];
    off[i] = o;
    cur[i] = o;
  }
}

__global__ void k_scatter(const int* __restrict__ ei, const int* __restrict__ flag,
                          int* __restrict__ cur, int* __restrict__ pos,
                          int* __restrict__ ssrc, int E) {
  int e = blockIdx.x * blockDim.x + threadIdx.x;
  if (e < E) {
    int is32 = *flag;
    int d = load_idx(ei, E + e, is32);
    int s = load_idx(ei, e, is32);
    int p = atomicAdd(&cur[d], 1);
    pos[e] = p;
    ssrc[p] = s;
  }
}

// ---------------- weight prep (layer 2 only) ----------------

__global__ void k_fold_att(const float* __restrict__ W, const float* __restrict__ att,
                           float* __restrict__ waj, float* __restrict__ wai,
                           int Cin, int H) {
  int i = blockIdx.x * blockDim.x + threadIdx.x;
  if (i >= Cin * H) return;
  int k = i / H, h = i % H;
  float sj = 0.f, si = 0.f;
  for (int d = 0; d < 64; ++d) {
    float w = W[k * (H * 64) + h * 64 + d];
    sj = fmaf(w, att[h * 192 + d], sj);
    si = fmaf(w, att[h * 192 + 64 + d], si);
  }
  waj[k * H + h] = sj;
  wai[k * H + h] = si;
}

template <int CIN, int H>
__global__ void k_node_dots(const float* __restrict__ xin, const float* __restrict__ waj,
                            const float* __restrict__ wai, float* __restrict__ ajd,
                            float* __restrict__ aid, int N) {
  int n = blockIdx.x * blockDim.x + threadIdx.x;
  if (n >= N) return;
  float sj[H], si[H];
#pragma unroll
  for (int h = 0; h < H; ++h) { sj[h] = 0.f; si[h] = 0.f; }
  const float* xr = xin + (size_t)n * CIN;
#pragma unroll 4
  for (int k = 0; k < CIN; ++k) {
    float xv = xr[k];
#pragma unroll
    for (int h = 0; h < H; ++h) {
      sj[h] = fmaf(xv, waj[k * H + h], sj[h]);
      si[h] = fmaf(xv, wai[k * H + h], si[h]);
    }
  }
#pragma unroll
  for (int h = 0; h < H; ++h) {
    ajd[(size_t)n * H + h] = sj[h];
    aid[(size_t)n * H + h] = si[h];
  }
}

// ---------------- per-node projection GEMM with fused att-dots (layers 0,1) ----------------
template <int F>
__global__ __launch_bounds__(256) void k_gemm_nh(
    const float* __restrict__ xin, const float* __restrict__ W,
    const float* __restrict__ att, float* __restrict__ xh,
    float* __restrict__ ajd, float* __restrict__ aid, int N) {
  const int wave = threadIdx.x >> 6, lane = threadIdx.x & 63;
  float w[F];
#pragma unroll
  for (int k = 0; k < F; ++k) w[k] = W[k * 64 + lane];
  const float aj = att[lane], ai = att[64 + lane];
  for (int n = blockIdx.x * 4 + wave; n < N; n += gridDim.x * 4) {
    const float* xr = xin + (size_t)n * F;
    float a = 0.f;
#pragma unroll
    for (int k = 0; k < F; ++k) a = fmaf(xr[k], w[k], a);
    xh[(size_t)n * 64 + lane] = a;
    float sj = a * aj, si = a * ai;
#pragma unroll
    for (int o = 32; o > 0; o >>= 1) {
      sj += __shfl_xor(sj, o, 64);
      si += __shfl_xor(si, o, 64);
    }
    if (lane == 0) { ajd[n] = sj; aid[n] = si; }
  }
}

// ---------------- bf16 split helpers ----------------

__device__ __forceinline__ unsigned short bf16_rne(float x) {
  unsigned int u = __float_as_uint(x);
  return (unsigned short)((u + 0x7FFFu + ((u >> 16) & 1u)) >> 16);
}

// ---------------- MFMA-based edge scalar ep ----------------

__global__ void k_prep_b(const float* __restrict__ We0, const float* __restrict__ We1,
                         const float* __restrict__ We2,
                         const float* __restrict__ att0, const float* __restrict__ att1,
                         const float* __restrict__ att2,
                         bf16x8* __restrict__ B1, bf16x8* __restrict__ B2,
                         float* __restrict__ avec) {
  int i = blockIdx.x * blockDim.x + threadIdx.x;
  if (i < 24 * 64) {
    int T = i >> 6, l = i & 63;
    int col = T * 16 + (l & 15);
    int grp = l >> 4;
    bf16x8 b1, b2;
#pragma unroll
    for (int j = 0; j < 8; ++j) {
      int kk = grp * 8 + j;     // 0..31
      int ks = kk & 15;         // source k (both halves use same Whi)
      float w;
      if (col < 64)        w = We0[ks * 64 + col];
      else if (col < 128)  w = We1[ks * 64 + (col - 64)];
      else                 w = We2[ks * 256 + (col - 128)];
      unsigned short hi = bf16_rne(w);
      float hif = __uint_as_float((unsigned int)hi << 16);
      unsigned short lo = bf16_rne(w - hif);
      b1[j] = (short)hi;
      b2[j] = (kk < 16) ? (short)lo : (short)0;
    }
    B1[i] = b1;
    B2[i] = b2;
  } else if (i < 24 * 64 + 384) {
    int col = i - 24 * 64;
    float a;
    if (col < 64)        a = att0[128 + col];
    else if (col < 128)  a = att1[128 + (col - 64)];
    else {
      int c = col - 128;
      a = att2[(c >> 6) * 192 + 128 + (c & 63)];
    }
    avec[col] = a;
  }
}

__global__ __launch_bounds__(256) void k_ep_mfma(
    const float* __restrict__ ea, const bf16x8* __restrict__ B1,
    const bf16x8* __restrict__ B2, const float* __restrict__ avec,
    const int* __restrict__ pos, float* __restrict__ ep0,
    float* __restrict__ ep1, float* __restrict__ ep2, int E) {
  const int lane = threadIdx.x & 63;
  const int wv = threadIdx.x >> 6;
  const long e0 = ((long)blockIdx.x * 4 + wv) * 64;
  const int grp = lane >> 4;        // 0..3
  const int row = lane & 15;        // edge index within fragment (B: N-col)
  const int kc = (grp & 1) * 8;     // which 8 source-k's this lane group loads
  const bool lo_grp = grp >= 2;     // groups 2,3 carry the lo halves (k 16..31)

  // ---- edge fragments (B operand) ----
  bf16x8 Bf[4];
#pragma unroll
  for (int f = 0; f < 4; ++f) {
    long e = e0 + f * 16 + row;
    if (e >= E) e = E - 1;          // clamp; stores guarded later
    const float* ar = ea + e * 16 + kc;
    float4 u0 = *reinterpret_cast<const float4*>(ar);
    float4 u1 = *reinterpret_cast<const float4*>(ar + 4);
    float v0 = u0.x, v1 = u0.y, v2 = u0.z, v3 = u0.w;
    float v4 = u1.x, v5 = u1.y, v6 = u1.z, v7 = u1.w;
    bf16x8 a;
#define CVT(J, V)                                                        \
    {                                                                    \
      unsigned short hi = bf16_rne(V);                                   \
      float hif = __uint_as_float((unsigned int)hi << 16);               \
      unsigned short lo = bf16_rne((V) - hif);                           \
      a[J] = (short)(lo_grp ? lo : hi);                                  \
    }
    CVT(0, v0) CVT(1, v1) CVT(2, v2) CVT(3, v3)
    CVT(4, v4) CVT(5, v5) CVT(6, v6) CVT(7, v7)
#undef CVT
    Bf[f] = a;
  }

  // ---- CSR positions (hoisted; used by lanes 0..15) ----
  int pf[4];
#pragma unroll
  for (int f = 0; f < 4; ++f) {
    long e = e0 + f * 16 + row;
    pf[f] = pos[e < E ? e : (E - 1)];
  }

  float4 v2acc[4];

  // ---- 6 segments x 4 tiles, d on the M (row) side ----
#pragma unroll
  for (int seg = 0; seg < 6; ++seg) {
    float sp0 = 0.f, sp1 = 0.f, sp2 = 0.f, sp3 = 0.f;
#pragma unroll
    for (int tt = 0; tt < 4; ++tt) {
      const int T = seg * 4 + tt;
      bf16x8 a1 = B1[T * 64 + lane];
      bf16x8 a2 = B2[T * 64 + lane];
      // a_p values for this lane's 4 d-rows: d = T*16 + grp*4 + r
      float4 av = *reinterpret_cast<const float4*>(avec + T * 16 + (grp << 2));
#define EPTILE(SP, F)                                                     \
      {                                                                   \
        f32x4 acc = {0.f, 0.f, 0.f, 0.f};                                 \
        acc = __builtin_amdgcn_mfma_f32_16x16x32_bf16(a1, Bf[F], acc, 0, 0, 0); \
        acc = __builtin_amdgcn_mfma_f32_16x16x32_bf16(a2, Bf[F], acc, 0, 0, 0); \
        SP = fmaf(fmaxf(acc[0], 0.f), av.x, SP);                          \
        SP = fmaf(fmaxf(acc[1], 0.f), av.y, SP);                          \
        SP = fmaf(fmaxf(acc[2], 0.f), av.z, SP);                          \
        SP = fmaf(fmaxf(acc[3], 0.f), av.w, SP);                          \
      }
      EPTILE(sp0, 0) EPTILE(sp1, 1) EPTILE(sp2, 2) EPTILE(sp3, 3)
#undef EPTILE
    }
    // combine the 4 lane-groups (each holds a quarter of the 64 d's)
    sp0 += __shfl_xor(sp0, 16, 64); sp0 += __shfl_xor(sp0, 32, 64);
    sp1 += __shfl_xor(sp1, 16, 64); sp1 += __shfl_xor(sp1, 32, 64);
    sp2 += __shfl_xor(sp2, 16, 64); sp2 += __shfl_xor(sp2, 32, 64);
    sp3 += __shfl_xor(sp3, 16, 64); sp3 += __shfl_xor(sp3, 32, 64);

    float spf[4] = {sp0, sp1, sp2, sp3};
    if (seg == 0) {
      if (lane < 16) {
#pragma unroll
        for (int f = 0; f < 4; ++f)
          if (e0 + f * 16 + lane < E) ep0[pf[f]] = spf[f];
      }
    } else if (seg == 1) {
      if (lane < 16) {
#pragma unroll
        for (int f = 0; f < 4; ++f)
          if (e0 + f * 16 + lane < E) ep1[pf[f]] = spf[f];
      }
    } else {
#pragma unroll
      for (int f = 0; f < 4; ++f) {
        if (seg == 2) v2acc[f].x = spf[f];
        if (seg == 3) v2acc[f].y = spf[f];
        if (seg == 4) v2acc[f].z = spf[f];
        if (seg == 5) v2acc[f].w = spf[f];
      }
    }
  }
  if (lane < 16) {
#pragma unroll
    for (int f = 0; f < 4; ++f)
      if (e0 + f * 16 + lane < E)
        reinterpret_cast<float4*>(ep2)[pf[f]] = v2acc[f];
  }
}

// ---------------- MFMA post GEMM (layer 2) ----------------

__global__ void k_prep_w2(const float* __restrict__ W2,
                          bf16x8* __restrict__ C1, bf16x8* __restrict__ C2) {
  int i = blockIdx.x * blockDim.x + threadIdx.x;
  if (i >= 16 * 4 * 64) return;
  int l = i & 63;
  int c = (i >> 6) & 3;
  int T = i >> 8;
  int col = T * 16 + (l & 15);
  int g = l >> 4;
  bf16x8 b1, b2;
#pragma unroll
  for (int j = 0; j < 8; ++j) {
    int kk = g * 8 + j;
    int ks = kk & 15;
    float w = W2[(size_t)(c * 16 + ks) * 256 + col];
    unsigned short hi = bf16_rne(w);
    float hif = __uint_as_float((unsigned int)hi << 16);
    unsigned short lo = bf16_rne(w - hif);
    b1[j] = (short)hi;
    b2[j] = (kk < 16) ? (short)lo : (short)0;
  }
  C1[i] = b1;
  C2[i] = b2;
}

__global__ __launch_bounds__(256) void k_post_mfma(
    const float* __restrict__ agg, const bf16x8* __restrict__ C1,
    const bf16x8* __restrict__ C2, float* __restrict__ out, int N) {
  const int lane = threadIdx.x & 63;
  const int wv = threadIdx.x >> 6;
  const int task = blockIdx.x * 4 + wv;
  const int ntask = (N + 15) / 16;
  if (task >= ntask) return;
  const int n0 = task * 16;
  const int g = lane >> 4;
  const int r = lane & 15;
  const int kc = (g & 1) * 8;
  const bool lo_grp = g >= 2;
  const int nrow = min(n0 + r, N - 1);   // clamp; stores guarded

  // ---- A fragments: [head][chunk], 8 agg values each ----
  bf16x8 A[4][4];
#pragma unroll
  for (int h = 0; h < 4; ++h)
#pragma unroll
    for (int c = 0; c < 4; ++c) {
      const float* ar = agg + (size_t)nrow * 256 + h * 64 + c * 16 + kc;
      float4 u0 = *reinterpret_cast<const float4*>(ar);
      float4 u1 = *reinterpret_cast<const float4*>(ar + 4);
      float v0 = u0.x, v1 = u0.y, v2 = u0.z, v3 = u0.w;
      float v4 = u1.x, v5 = u1.y, v6 = u1.z, v7 = u1.w;
      bf16x8 a;
#define CVT(J, V)                                                        \
      {                                                                  \
        unsigned short hi = bf16_rne(V);                                 \
        float hif = __uint_as_float((unsigned int)hi << 16);             \
        unsigned short lo = bf16_rne((V) - hif);                         \
        a[J] = (short)(lo_grp ? lo : hi);                                \
      }
      CVT(0, v0) CVT(1, v1) CVT(2, v2) CVT(3, v3)
      CVT(4, v4) CVT(5, v5) CVT(6, v6) CVT(7, v7)
#undef CVT
      A[h][c] = a;
    }

  // ---- 16 col-tiles: K-accumulate over 4 chunks x 2 MFMAs ----
#pragma unroll
  for (int T = 0; T < 16; ++T) {
    const int h = T >> 2;
    f32x4 acc = {0.f, 0.f, 0.f, 0.f};
#pragma unroll
    for (int c = 0; c < 4; ++c) {
      bf16x8 b1 = C1[(T * 4 + c) * 64 + lane];
      bf16x8 b2 = C2[(T * 4 + c) * 64 + lane];
      acc = __builtin_amdgcn_mfma_f32_16x16x32_bf16(A[h][c], b1, acc, 0, 0, 0);
      acc = __builtin_amdgcn_mfma_f32_16x16x32_bf16(A[h][c], b2, acc, 0, 0, 0);
    }
#pragma unroll
    for (int q = 0; q < 4; ++q) {
      int n = n0 + g * 4 + q;
      if (n < N) out[(size_t)n * 256 + T * 16 + r] = acc[q];
    }
  }
}

// ---------------- fused attention softmax + aggregate ----------------

template <int H>
__device__ __forceinline__ void loadH(const float* __restrict__ p, float* v) {
  if constexpr (H == 4) {
    float4 t = *reinterpret_cast<const float4*>(p);
    v[0] = t.x; v[1] = t.y; v[2] = t.z; v[3] = t.w;
  } else {
    v[0] = *p;
  }
}

// one wave per node, all H heads together.
// Fast path (deg <= 64): lane i owns edge i — score computed ONCE, two butterfly
// reduces (max, sum), alpha stays in-lane -> LDS; accumulation 8-way unrolled.
// Slow path (deg > 64): original two-pass online-softmax code (correctness).
template <int F, int H, bool ELU_OUT>
__global__ __launch_bounds__(256) void k_attn_agg(
    const int* __restrict__ off, const int* __restrict__ ssrc,
    const float* __restrict__ hin, const float* __restrict__ ajd,
    const float* __restrict__ aid, const float* __restrict__ ep,
    float* __restrict__ outbuf, int N) {
  constexpr int FPL = F / 64;
  __shared__ float ls_alpha[4][64 * H];
  __shared__ int ls_src[4][64];
  const int wave = threadIdx.x >> 6, lane = threadIdx.x & 63;
  float* const la = ls_alpha[wave];
  int* const lsrc = ls_src[wave];

  for (int n = blockIdx.x * 4 + wave; n < N; n += gridDim.x * 4) {
    const int o0 = off[n];
    const int deg = off[n + 1] - o0;
    float aidn[H];
    loadH<H>(aid + (size_t)n * H, aidn);

    float acc[H][FPL];
#pragma unroll
    for (int h = 0; h < H; ++h)
#pragma unroll
      for (int c = 0; c < FPL; ++c) acc[h][c] = 0.f;

    if (deg <= 64) {
      // ---- fast path: single gather round ----
      const bool act = lane < deg;
      float sc[H];
      int sr = 0;
      if (act) {
        sr = ssrc[o0 + lane];
        float aj[H], pv[H];
        loadH<H>(ajd + (size_t)sr * H, aj);
        loadH<H>(ep + (size_t)(o0 + lane) * H, pv);
#pragma unroll
        for (int h = 0; h < H; ++h) {
          float v = aj[h] + aidn[h] + pv[h];
          sc[h] = v > 0.f ? v : 0.2f * v;
        }
      } else {
#pragma unroll
        for (int h = 0; h < H; ++h) sc[h] = -1e30f;
      }
      float m[H];
#pragma unroll
      for (int h = 0; h < H; ++h) m[h] = sc[h];
#pragma unroll
      for (int o = 32; o > 0; o >>= 1)
#pragma unroll
        for (int h = 0; h < H; ++h)
          m[h] = fmaxf(m[h], __shfl_xor(m[h], o, 64));
      float al[H], s[H];
#pragma unroll
      for (int h = 0; h < H; ++h) {
        al[h] = act ? __expf(sc[h] - m[h]) : 0.f;
        s[h] = al[h];
      }
#pragma unroll
      for (int o = 32; o > 0; o >>= 1)
#pragma unroll
        for (int h = 0; h < H; ++h)
          s[h] += __shfl_xor(s[h], o, 64);
      if (act) {
        lsrc[lane] = sr;
#pragma unroll
        for (int h = 0; h < H; ++h)
          la[lane * H + h] = al[h] / (s[h] + 1e-16f);
      }
      asm volatile("s_waitcnt lgkmcnt(0)" ::: "memory");

      int j = 0;
      for (; j + 8 <= deg; j += 8) {
        int srj[8];
        float av[8][H];
#pragma unroll
        for (int u = 0; u < 8; ++u) {
          srj[u] = lsrc[j + u];
          loadH<H>(la + (j + u) * H, av[u]);
        }
        float v[8][FPL];
#pragma unroll
        for (int u = 0; u < 8; ++u) {
          const float* hr = hin + (size_t)srj[u] * F + lane;
#pragma unroll
          for (int c = 0; c < FPL; ++c) v[u][c] = hr[c * 64];
        }
#pragma unroll
        for (int u = 0; u < 8; ++u)
#pragma unroll
          for (int h = 0; h < H; ++h)
#pragma unroll
            for (int c = 0; c < FPL; ++c)
              acc[h][c] = fmaf(av[u][h], v[u][c], acc[h][c]);
      }
      for (; j < deg; ++j) {
        int sr2 = lsrc[j];
        float av[H];
        loadH<H>(la + j * H, av);
        const float* hr = hin + (size_t)sr2 * F + lane;
#pragma unroll
        for (int h = 0; h < H; ++h)
#pragma unroll
          for (int c = 0; c < FPL; ++c)
            acc[h][c] = fmaf(av[h], hr[c * 64], acc[h][c]);
      }
    } else {
      // ---- slow path: original two-pass online softmax ----
      float m[H], s[H];
#pragma unroll
      for (int h = 0; h < H; ++h) { m[h] = -1e30f; s[h] = 0.f; }
      for (int i = lane; i < deg; i += 64) {
        int sr = ssrc[o0 + i];
        float aj[H], pv[H];
        loadH<H>(ajd + (size_t)sr * H, aj);
        loadH<H>(ep + (size_t)(o0 + i) * H, pv);
#pragma unroll
        for (int h = 0; h < H; ++h) {
          float sc = aj[h] + aidn[h] + pv[h];
          sc = sc > 0.f ? sc : 0.2f * sc;
          float mn = fmaxf(m[h], sc);
          s[h] = s[h] * __expf(m[h] - mn) + __expf(sc - mn);
          m[h] = mn;
        }
      }
#pragma unroll
      for (int o = 32; o > 0; o >>= 1) {
#pragma unroll
        for (int h = 0; h < H; ++h) {
          float m2 = __shfl_xor(m[h], o, 64);
          float s2 = __shfl_xor(s[h], o, 64);
          float mn = fmaxf(m[h], m2);
          s[h] = s[h] * __expf(m[h] - mn) + s2 * __expf(m2 - mn);
          m[h] = mn;
        }
      }
      float inv[H];
#pragma unroll
      for (int h = 0; h < H; ++h) inv[h] = 1.f / (s[h] + 1e-16f);

      for (int base = 0; base < deg; base += 64) {
        const int cnt = min(64, deg - base);
        if (lane < cnt) {
          int i = base + lane;
          int sr = ssrc[o0 + i];
          lsrc[lane] = sr;
          float aj[H], pv[H];
          loadH<H>(ajd + (size_t)sr * H, aj);
          loadH<H>(ep + (size_t)(o0 + i) * H, pv);
#pragma unroll
          for (int h = 0; h < H; ++h) {
            float sc = aj[h] + aidn[h] + pv[h];
            sc = sc > 0.f ? sc : 0.2f * sc;
            la[lane * H + h] = __expf(sc - m[h]) * inv[h];
          }
        }
        asm volatile("s_waitcnt lgkmcnt(0)" ::: "memory");

        int j = 0;
        for (; j + 4 <= cnt; j += 4) {
          int srj[4];
          float av[4][H];
#pragma unroll
          for (int u = 0; u < 4; ++u) {
            srj[u] = lsrc[j + u];
            loadH<H>(la + (j + u) * H, av[u]);
          }
          float v[4][FPL];
#pragma unroll
          for (int u = 0; u < 4; ++u) {
            const float* hr = hin + (size_t)srj[u] * F + lane;
#pragma unroll
            for (int c = 0; c < FPL; ++c) v[u][c] = hr[c * 64];
          }
#pragma unroll
          for (int u = 0; u < 4; ++u)
#pragma unroll
            for (int h = 0; h < H; ++h)
#pragma unroll
              for (int c = 0; c < FPL; ++c)
                acc[h][c] = fmaf(av[u][h], v[u][c], acc[h][c]);
        }
        for (; j < cnt; ++j) {
          int sr = lsrc[j];
          float av[H];
          loadH<H>(la + j * H, av);
          const float* hr = hin + (size_t)sr * F + lane;
#pragma unroll
          for (int h = 0; h < H; ++h)
#pragma unroll
            for (int c = 0; c < FPL; ++c)
              acc[h][c] = fmaf(av[h], hr[c * 64], acc[h][c]);
        }
      }
    }

    float* ob = outbuf + (size_t)n * (H * F);
#pragma unroll
    for (int h = 0; h < H; ++h)
#pragma unroll
      for (int c = 0; c < FPL; ++c) {
        float v = acc[h][c];
        if (ELU_OUT) v = (v > 0.f) ? v : expm1f(v);
        ob[h * F + c * 64 + lane] = v;
      }
  }
}

// ---------------- launch ----------------

extern "C" void kernel_launch(void* const* d_in, const int* in_sizes, int n_in,
                              void* d_out, int out_size, void* d_ws, size_t ws_size,
                              hipStream_t stream) {
  const float* x    = (const float*)d_in[0];
  const int*   ei   = (const int*)d_in[1];
  const float* ea   = (const float*)d_in[2];
  const float* W0   = (const float*)d_in[3];
  const float* We0  = (const float*)d_in[4];
  const float* att0 = (const float*)d_in[5];
  const float* W1   = (const float*)d_in[6];
  const float* We1  = (const float*)d_in[7];
  const float* att1 = (const float*)d_in[8];
  const float* W2   = (const float*)d_in[9];
  const float* We2  = (const float*)d_in[10];
  const float* att2 = (const float*)d_in[11];
  float* out = (float*)d_out;

  const int N = in_sizes[0] / 128;   // 50000
  const int E = in_sizes[2] / 16;    // 800000

  char* p = (char*)d_ws;
  auto alloc = [&](size_t bytes) {
    char* r = p;
    p += (bytes + 255) & ~(size_t)255;
    return r;
  };
  int*   flag = (int*)  alloc(sizeof(int));
  int*   off  = (int*)  alloc((size_t)(N + 1) * sizeof(int));
  int*   cur  = (int*)  alloc((size_t)N * sizeof(int));
  int*   bsum = (int*)  alloc(256 * sizeof(int));
  int*   boff = (int*)  alloc(256 * sizeof(int));
  int*   pos  = (int*)  alloc((size_t)E * sizeof(int));
  int*   ssrc = (int*)  alloc((size_t)E * sizeof(int));
  bf16x8* B1  = (bf16x8*)alloc(24 * 64 * sizeof(bf16x8));
  bf16x8* B2  = (bf16x8*)alloc(24 * 64 * sizeof(bf16x8));
  bf16x8* C1  = (bf16x8*)alloc(64 * 64 * sizeof(bf16x8));
  bf16x8* C2  = (bf16x8*)alloc(64 * 64 * sizeof(bf16x8));
  float* avec = (float*)alloc(384 * sizeof(float));
  float* waj2 = (float*)alloc(256 * sizeof(float));
  float* wai2 = (float*)alloc(256 * sizeof(float));
  float* ajdA = (float*)alloc((size_t)N * sizeof(float));
  float* aidA = (float*)alloc((size_t)N * sizeof(float));
  float* ajd2 = (float*)alloc((size_t)N * 4 * sizeof(float));
  float* aid2 = (float*)alloc((size_t)N * 4 * sizeof(float));
  float* ep0  = (float*)alloc((size_t)E * sizeof(float));
  float* ep1  = (float*)alloc((size_t)E * sizeof(float));
  float* ep2  = (float*)alloc((size_t)E * 4 * sizeof(float));
  float* xh0  = (float*)alloc((size_t)N * 64 * sizeof(float));
  float* h1   = (float*)alloc((size_t)N * 64 * sizeof(float));
  float* xh1  = (float*)alloc((size_t)N * 64 * sizeof(float));
  float* h2   = (float*)alloc((size_t)N * 64 * sizeof(float));
  float* aggL2= (float*)alloc((size_t)N * 256 * sizeof(float));

  const int eb = (E + THR - 1) / THR;
  const int nb = (N + THR - 1) / THR;
  const int sb = (N + 255) / 256;           // scan blocks (196 <= 256)
  const int ab = (N + 3) / 4;
  const int gb = min(ab, 2048);
  const int pb = ((N + 15) / 16 + 3) / 4;   // post-MFMA: 4 wave-tasks of 16 nodes per block

  hipMemsetAsync(flag, 0, sizeof(int), stream);
  hipMemsetAsync(cur, 0, (size_t)N * sizeof(int), stream);

  k_detect<<<16, THR, 0, stream>>>(ei, flag);
  k_count<<<eb, THR, 0, stream>>>(ei, flag, cur, E);
  k_scan1<<<sb, 256, 0, stream>>>(cur, off, bsum, N);
  k_scan2<<<1, 256, 0, stream>>>(bsum, boff, off, sb, N);
  k_scan3<<<sb, 256, 0, stream>>>(off, boff, cur, N);
  k_scatter<<<eb, THR, 0, stream>>>(ei, flag, cur, pos, ssrc, E);

  k_prep_b<<<8, THR, 0, stream>>>(We0, We1, We2, att0, att1, att2, B1, B2, avec);
  k_prep_w2<<<16, THR, 0, stream>>>(W2, C1, C2);
  // 256 edges per block (4 waves x 64 edges)
  k_ep_mfma<<<(E + 255) / 256, THR, 0, stream>>>(ea, B1, B2, avec, pos,
                                                 ep0, ep1, ep2, E);

  // layer 0: xh0 = x@W0 (+ fused a_j/a_i dots), aggregate in output space, ELU fused
  k_gemm_nh<128><<<gb, THR, 0, stream>>>(x, W0, att0, xh0, ajdA, aidA, N);
  k_attn_agg<64, 1, true><<<ab, THR, 0, stream>>>(off, ssrc, xh0, ajdA, aidA, ep0, h1, N);

  // layer 1: xh1 = h1@W1, aggregate, ELU fused
  k_gemm_nh<64><<<gb, THR, 0, stream>>>(h1, W1, att1, xh1, ajdA, aidA, N);
  k_attn_agg<64, 1, true><<<ab, THR, 0, stream>>>(off, ssrc, xh1, ajdA, aidA, ep1, h2, N);

  // layer 2: input-space aggregation (64 < 4*64), then MFMA post GEMM
  k_fold_att<<<1, 256, 0, stream>>>(W2, att2, waj2, wai2, 64, 4);
  k_node_dots<64, 4><<<nb, THR, 0, stream>>>(h2, waj2, wai2, ajd2, aid2, N);
  k_attn_agg<64, 4, false><<<ab, THR, 0, stream>>>(off, ssrc, h2, ajd2, aid2, ep2, aggL2, N);
  k_post_mfma<<<pb, THR, 0, stream>>>(aggL2, C1, C2, out, N);
}